// Round 16
// baseline (165.547 us; speedup 1.0000x reference)
//
#include <hip/hip_runtime.h>
#include <hip/hip_bf16.h>

#define NN 50000
#define EE 800000
#define NEG 0.2f
#define NSH 8            // shards
#define NS (NN*NSH)      // scan length: (node, shard) pairs = 400000
#define NSB2 98          // scan blocks: ceil(NS/4096)
#define NZB 98           // deg-zero blocks in k_pre_all
#define NGB 1563         // gemm blocks: ceil(NN/32)
#define NDB 782          // deg blocks:  ceil(EE/1024)

using u32 = unsigned int;
typedef short short4v __attribute__((ext_vector_type(4)));
typedef float f32x4 __attribute__((ext_vector_type(4)));
typedef unsigned int u32x4 __attribute__((ext_vector_type(4)));

__device__ __forceinline__ unsigned short f2bf(float f){
  u32 b = __float_as_uint(f);
  b += 0x7FFFu + ((b >> 16) & 1u);        // RNE; inputs finite
  return (unsigned short)(b >> 16);
}

// ---- K0: merged precompute + deg8 zeroing (unchanged from R15) ----
__global__ __launch_bounds__(256) void k_pre_all(
        const float* __restrict__ Wg, const float* __restrict__ W_c,
        const float* __restrict__ W_edge, const float* __restrict__ att_edge,
        const float* __restrict__ b_c, const float* __restrict__ ns,
        const float* __restrict__ b_gat,
        const float* __restrict__ att_src, const float* __restrict__ att_dst,
        unsigned short* __restrict__ WzB, float* __restrict__ Wt,
        float* __restrict__ cvec, uint2* __restrict__ avp,
        u32* __restrict__ deg8){
  int bid = blockIdx.x, tid = threadIdx.x;
  if (bid < 128){
    __shared__ float sWg[256];
    __shared__ float sWc[64*64];
    sWg[tid] = Wg[bid*256 + tid];
    for (int i = tid; i < 4096; i += 256) sWc[i] = W_c[i];
    __syncthreads();
    int h = tid >> 6, j = tid & 63;
    float s = 0.f;
    #pragma unroll 8
    for (int c = 0; c < 64; c++) s += sWg[h*64 + c] * sWc[c*64 + j];
    int t = tid >> 4, lr = tid & 15;
    int ks = bid >> 4, lg = (bid >> 2) & 3, q = bid & 3;
    int l = lg*16 + lr;
    WzB[(((t*8 + ks)*64 + l) << 2) + q] = f2bf(s);
  } else if (bid == 128){
    if (tid < 64){
      int d = tid >> 2, h = tid & 3;
      float s = 0.f;
      for (int c = 0; c < 64; c++) s += W_edge[d*256 + h*64 + c] * att_edge[h*64 + c];
      Wt[d*4 + h] = s;
    } else if (tid < 128){
      int j = tid - 64;
      float s = b_c[j];
      for (int d = 0; d < 16; d++) s += ns[d >> 1] * W_c[(64 + d)*64 + j];
      for (int c = 0; c < 64; c++) s += b_gat[c] * W_c[c*64 + j];
      cvec[j] = s;
    }
  } else if (bid == 129){
    __shared__ float sav2[1024];       // [k][o] o: 0-3 src, 4-7 dst
    for (int i = tid; i < 1024; i += 256){
      int k = i >> 3, o = i & 7, h = o & 3;
      const float* att = (o < 4) ? att_src : att_dst;
      float s = 0.f;
      for (int c = 0; c < 64; c++) s += Wg[k*256 + h*64 + c] * att[h*64 + c];
      sav2[i] = s;
    }
    __syncthreads();
    if (tid < 64){
      int l = tid, lg = l >> 4, lr = l & 15;
      for (int ks = 0; ks < 8; ks++){
        unsigned int h0, h1, h2, h3;
        int kb = ks*16 + lg*4;
        h0 = (lr < 8) ? f2bf(sav2[(kb+0)*8 + lr]) : 0u;
        h1 = (lr < 8) ? f2bf(sav2[(kb+1)*8 + lr]) : 0u;
        h2 = (lr < 8) ? f2bf(sav2[(kb+2)*8 + lr]) : 0u;
        h3 = (lr < 8) ? f2bf(sav2[(kb+3)*8 + lr]) : 0u;
        uint2 u; u.x = h0 | (h1 << 16); u.y = h2 | (h3 << 16);
        avp[ks*64 + l] = u;
      }
    }
  } else {
    u32x4 z = {0u,0u,0u,0u};
    int slot0 = ((bid - 130)*256 + tid)*4;
    #pragma unroll
    for (int i = 0; i < 4; i++){
      int slot = slot0 + i;
      if (slot*4 < NS) *(u32x4*)(deg8 + slot*4) = z;
    }
  }
}

// ---- K1: heterogeneous main kernel (unchanged from R15) ----
__global__ __launch_bounds__(256) void k_main(const float* __restrict__ x,
        const unsigned short* __restrict__ WzB, const uint2* __restrict__ avp,
        const int* __restrict__ dsts,
        __hip_bfloat16* __restrict__ zs,
        float* __restrict__ a_src, float* __restrict__ a_dst,
        u32* __restrict__ deg8, unsigned short* __restrict__ rank){
  __shared__ alignas(16) char ldsu[17408];
  int tid = threadIdx.x;
  int bid = blockIdx.x;

  if ((bid % 3) == 1){
    int g = bid / 3;
    int gi = g*256 + tid;
    if (gi*4 < EE){
      int shard = g & (NSH-1);
      int4 d4 = *(const int4*)(dsts + (size_t)gi*4);
      u32 r0 = atomicAdd(&deg8[((size_t)(u32)d4.x << 3) | shard], 1u);
      u32 r1 = atomicAdd(&deg8[((size_t)(u32)d4.y << 3) | shard], 1u);
      u32 r2 = atomicAdd(&deg8[((size_t)(u32)d4.z << 3) | shard], 1u);
      u32 r3 = atomicAdd(&deg8[((size_t)(u32)d4.w << 3) | shard], 1u);
      uint2 pk;
      pk.x = (r0 & 0xffffu) | (r1 << 16);
      pk.y = (r2 & 0xffffu) | (r3 << 16);
      *(uint2*)(rank + (size_t)gi*4) = pk;
    }
    return;
  }

  int gb = bid - (bid + 2)/3;
  int w = tid >> 6, l = tid & 63;
  int lr = l & 15, lg = l >> 4;
  int rw = w >> 1, ch = w & 1;
  int nb = gb*32;
  int n0 = nb + rw*16;

  float* xsl = (float*)ldsu;
  __hip_bfloat16* ztp = (__hip_bfloat16*)ldsu;

  {
    float4 stg[4];
    #pragma unroll
    for (int i = 0; i < 4; i++){
      int s = w*256 + i*64 + l;
      int r = s >> 5, c = s & 31;
      int row = nb + r; if (row >= NN) row = NN - 1;
      stg[i] = *(const float4*)(x + (size_t)row*128 + c*4);
    }
    #pragma unroll
    for (int i = 0; i < 4; i++){
      int s = w*256 + i*64 + l;
      *(float4*)(xsl + s*4) = stg[i];
    }
  }
  __syncthreads();

  short4v afr[8];
  #pragma unroll
  for (int ks = 0; ks < 8; ks++){
    float4 xa = *(const float4*)(xsl + ((rw*16 + lr)*128 + ks*16 + lg*4));
    short4v a;
    a[0] = (short)f2bf(xa.x); a[1] = (short)f2bf(xa.y);
    a[2] = (short)f2bf(xa.z); a[3] = (short)f2bf(xa.w);
    afr[ks] = a;
  }
  if (ch == 0){
    f32x4 cad = {0.f, 0.f, 0.f, 0.f};
    #pragma unroll
    for (int ks = 0; ks < 8; ks++){
      short4v b = __builtin_bit_cast(short4v, avp[ks*64 + l]);
      cad = __builtin_amdgcn_mfma_f32_16x16x16bf16_1k(afr[ks], b, cad, 0, 0, 0);
    }
    #pragma unroll
    for (int r = 0; r < 4; r++){
      int n = n0 + lg*4 + r;
      if (n < NN){
        if (lr < 4)      a_src[(size_t)n*4 + lr]       = cad[r];
        else if (lr < 8) a_dst[(size_t)n*4 + (lr - 4)] = cad[r];
      }
    }
  }
  __syncthreads();

  #pragma unroll 4
  for (int t8 = 0; t8 < 8; t8++){
    int t = ch*8 + t8;
    f32x4 c = {0.f, 0.f, 0.f, 0.f};
    #pragma unroll
    for (int ks = 0; ks < 8; ks++){
      short4v b = *(const short4v*)(WzB + (((t*8 + ks)*64 + l) << 2));
      c = __builtin_amdgcn_mfma_f32_16x16x16bf16_1k(afr[ks], b, c, 0, 0, 0);
    }
    #pragma unroll
    for (int r = 0; r < 4; r++)
      ztp[((w*16) + lg*4 + r)*136 + t8*16 + lr] = __float2bfloat16(c[r]);
  }
  #pragma unroll
  for (int i = 0; i < 4; i++){
    int f = i*64 + l;
    int row = f >> 4, c16 = f & 15;
    int n = n0 + row;
    if (n < NN)
      *(uint4*)(zs + (size_t)n*256 + ch*128 + c16*8) = *(const uint4*)&ztp[(w*16 + row)*136 + c16*8];
  }
}

// ---- K3a/K3b: scans (unchanged from R15) ----
__global__ __launch_bounds__(1024) void k_scan1(const u32* __restrict__ deg8,
                                                u32* __restrict__ offs8, u32* __restrict__ bsum){
  __shared__ u32 sd[1024];
  int t = threadIdx.x;
  size_t base = (size_t)blockIdx.x*4096 + (size_t)t*4;
  u32x4 v = {0u,0u,0u,0u};
  if (base < NS) v = *(const u32x4*)(deg8 + base);
  u32 o1 = v.x, o2 = o1 + v.y, o3 = o2 + v.z;
  u32 tsum = o3 + v.w;
  sd[t] = tsum; __syncthreads();
  for (int off = 1; off < 1024; off <<= 1){
    u32 u = (t >= off) ? sd[t-off] : 0u;
    __syncthreads();
    sd[t] += u;
    __syncthreads();
  }
  u32 excl = sd[t] - tsum;
  if (base < NS){
    u32x4 o = {excl, excl + o1, excl + o2, excl + o3};
    *(u32x4*)(offs8 + base) = o;
  }
  if (t == 1023) bsum[blockIdx.x] = sd[1023];
}

__global__ __launch_bounds__(1024) void k_scan2(u32* __restrict__ offs8,
                                                const u32* __restrict__ bsum){
  __shared__ u32 sd[1024];
  int b = blockIdx.x, t = threadIdx.x;
  sd[t] = (t < b) ? bsum[t] : 0u;
  __syncthreads();
  #pragma unroll
  for (int off = 512; off; off >>= 1){
    if (t < off) sd[t] += sd[t + off];
    __syncthreads();
  }
  u32 p = sd[0];
  size_t base = (size_t)b*4096 + (size_t)t*4;
  if (base < NS){
    u32x4 o = *(u32x4*)(offs8 + base);
    o.x += p; o.y += p; o.z += p; o.w += p;
    *(u32x4*)(offs8 + base) = o;
  }
  if (b == 0 && t == 0) offs8[NS] = EE;
}

// ---- K4: per-edge logits (unchanged from R15) ----
__global__ __launch_bounds__(256) void k_edge(const float* __restrict__ qraw,
        const float* __restrict__ eattr, const int* __restrict__ eidx,
        const float* __restrict__ Wq1, const float* __restrict__ bq1,
        const float* __restrict__ Wq2, const float* __restrict__ bq2,
        const float* __restrict__ Wt,
        const float* __restrict__ a_src,
        const u32* __restrict__ offs8, const unsigned short* __restrict__ rank,
        uint4* __restrict__ csr){
  __shared__ float sWq1[32], sbq1[8], sWq2[128], sbq2[16], sWt[64];
  int tid = threadIdx.x;
  if (tid < 32) sWq1[tid] = Wq1[tid];
  else if (tid < 40)  sbq1[tid-32]  = bq1[tid-32];
  else if (tid < 168) sWq2[tid-40]  = Wq2[tid-40];
  else if (tid < 184) sbq2[tid-168] = bq2[tid-168];
  else if (tid < 248) sWt[tid-184]  = Wt[tid-184];
  __syncthreads();
  int e = blockIdx.x*256 + tid;
  if (e >= EE) return;
  int shard = (blockIdx.x >> 2) & (NSH-1);

  int src = eidx[e], dst = eidx[EE + e];
  u32 rk = (u32)rank[e];
  float4 qr = *(const float4*)(qraw + (size_t)e*4);
  float4 as4 = *(const float4*)(a_src + (size_t)src*4);
  u32 base = offs8[((size_t)(u32)dst << 3) | shard];

  float t1[8];
  #pragma unroll
  for (int j = 0; j < 8; j++){
    float s = sbq1[j] + qr.x*sWq1[j] + qr.y*sWq1[8+j] + qr.z*sWq1[16+j] + qr.w*sWq1[24+j];
    t1[j] = fmaxf(s, 0.f);
  }
  float ae[4] = {0.f,0.f,0.f,0.f};
  const float* ea = eattr + (size_t)e*16;
  #pragma unroll
  for (int d = 0; d < 16; d++){
    float q = sbq2[d];
    #pragma unroll
    for (int j = 0; j < 8; j++) q += t1[j]*sWq2[j*16 + d];
    float v = ea[d] + q;
    #pragma unroll
    for (int h = 0; h < 4; h++) ae[h] += v * sWt[d*4 + h];
  }
  u32 pk0 = (u32)f2bf(as4.x + ae[0]);
  u32 pk1 = (u32)f2bf(as4.y + ae[1]);
  u32 pk2 = (u32)f2bf(as4.z + ae[2]);
  u32 pk3 = (u32)f2bf(as4.w + ae[3]);
  u32 pos = base + rk;
  uint4 q;
  q.x = (u32)src;
  q.y = pk0 | (pk1 << 16);
  q.z = pk2 | (pk3 << 16);
  q.w = 0u;
  csr[pos] = q;
}

// ---- K5: aggregation, TWO-PHASE channel split (heads 0-1 then 2-3) ----
// 32 lanes/node, 8B/lane/phase: phase1 touches bytes [0,256) of each z-row
// (12.8MB chip-wide working set), phase2 bytes [256,512). csr segment re-read
// in phase2 is L2-hot. Halved time-local working set -> higher L2 hit rate.
__global__ __launch_bounds__(256) void k_agg(const __hip_bfloat16* __restrict__ zs,
        const uint4* __restrict__ csr, const u32* __restrict__ offs8,
        const float* __restrict__ a_dst,
        const float* __restrict__ cvec, float* __restrict__ out){
  int tid = threadIdx.x;
  int w = tid >> 6, lane = tid & 63;
  int half = lane >> 5, sl = lane & 31;
  int n = blockIdx.x*8 + w*2 + half;    // grid = NN/8 exactly
  int hh = sl >> 4;                     // head within phase-pair (0 or 1)
  int c4 = sl & 15;                     // 4-channel group j = c4*4..+3
  u32 p0 = offs8[(size_t)n << 3], p1 = offs8[((size_t)n << 3) + 8];
  float advA = a_dst[((size_t)n << 2) + hh];        // head hh
  float advB = a_dst[((size_t)n << 2) + hh + 2];    // head hh+2
  int sh = hh ? 0 : 16;
  u32 lbA = (u32)(hh*128 + c4*8);       // phase1 byte offset within 512B row
  u32 lbB = lbA + 256u;                 // phase2
  const char* zb = (const char*)zs;

  float dA = 0.f, b0=0.f, b1=0.f, b2=0.f, b3=0.f;
  float dB = 0.f, c0=0.f, c1=0.f, c2=0.f, c3=0.f;
  u32 p;

  // ---- phase 1: heads 0-1 (csr .y), row bytes [0,256) ----
  for (p = p0; p + 4 <= p1; p += 4){
    uint4 q0 = csr[p+0], q1 = csr[p+1], q2 = csr[p+2], q3 = csr[p+3];
    uint2 v0 = *(const uint2*)(zb + (((u32)q0.x << 9) + lbA));
    uint2 v1 = *(const uint2*)(zb + (((u32)q1.x << 9) + lbA));
    uint2 v2 = *(const uint2*)(zb + (((u32)q2.x << 9) + lbA));
    uint2 v3 = *(const uint2*)(zb + (((u32)q3.x << 9) + lbA));
    float al0 = __uint_as_float((q0.y << sh) & 0xffff0000u) + advA;
    float al1 = __uint_as_float((q1.y << sh) & 0xffff0000u) + advA;
    float al2 = __uint_as_float((q2.y << sh) & 0xffff0000u) + advA;
    float al3 = __uint_as_float((q3.y << sh) & 0xffff0000u) + advA;
    al0 = fmaxf(al0, 0.f) + NEG*fminf(al0, 0.f);
    al1 = fmaxf(al1, 0.f) + NEG*fminf(al1, 0.f);
    al2 = fmaxf(al2, 0.f) + NEG*fminf(al2, 0.f);
    al3 = fmaxf(al3, 0.f) + NEG*fminf(al3, 0.f);
    float w0 = __expf(al0), w1 = __expf(al1), w2 = __expf(al2), w3 = __expf(al3);
    b0 += w0*__uint_as_float(v0.x << 16)         + w1*__uint_as_float(v1.x << 16)
        + w2*__uint_as_float(v2.x << 16)         + w3*__uint_as_float(v3.x << 16);
    b1 += w0*__uint_as_float(v0.x & 0xffff0000u) + w1*__uint_as_float(v1.x & 0xffff0000u)
        + w2*__uint_as_float(v2.x & 0xffff0000u) + w3*__uint_as_float(v3.x & 0xffff0000u);
    b2 += w0*__uint_as_float(v0.y << 16)         + w1*__uint_as_float(v1.y << 16)
        + w2*__uint_as_float(v2.y << 16)         + w3*__uint_as_float(v3.y << 16);
    b3 += w0*__uint_as_float(v0.y & 0xffff0000u) + w1*__uint_as_float(v1.y & 0xffff0000u)
        + w2*__uint_as_float(v2.y & 0xffff0000u) + w3*__uint_as_float(v3.y & 0xffff0000u);
    dA += (w0 + w1) + (w2 + w3);
  }
  for (; p < p1; p++){
    uint4 q0 = csr[p];
    uint2 v0 = *(const uint2*)(zb + (((u32)q0.x << 9) + lbA));
    float al = __uint_as_float((q0.y << sh) & 0xffff0000u) + advA;
    al = fmaxf(al, 0.f) + NEG*fminf(al, 0.f);
    float w0 = __expf(al);
    b0 += w0*__uint_as_float(v0.x << 16);
    b1 += w0*__uint_as_float(v0.x & 0xffff0000u);
    b2 += w0*__uint_as_float(v0.y << 16);
    b3 += w0*__uint_as_float(v0.y & 0xffff0000u);
    dA += w0;
  }

  // ---- phase 2: heads 2-3 (csr .z), row bytes [256,512); csr re-read L2-hot ----
  for (p = p0; p + 4 <= p1; p += 4){
    uint4 q0 = csr[p+0], q1 = csr[p+1], q2 = csr[p+2], q3 = csr[p+3];
    uint2 v0 = *(const uint2*)(zb + (((u32)q0.x << 9) + lbB));
    uint2 v1 = *(const uint2*)(zb + (((u32)q1.x << 9) + lbB));
    uint2 v2 = *(const uint2*)(zb + (((u32)q2.x << 9) + lbB));
    uint2 v3 = *(const uint2*)(zb + (((u32)q3.x << 9) + lbB));
    float al0 = __uint_as_float((q0.z << sh) & 0xffff0000u) + advB;
    float al1 = __uint_as_float((q1.z << sh) & 0xffff0000u) + advB;
    float al2 = __uint_as_float((q2.z << sh) & 0xffff0000u) + advB;
    float al3 = __uint_as_float((q3.z << sh) & 0xffff0000u) + advB;
    al0 = fmaxf(al0, 0.f) + NEG*fminf(al0, 0.f);
    al1 = fmaxf(al1, 0.f) + NEG*fminf(al1, 0.f);
    al2 = fmaxf(al2, 0.f) + NEG*fminf(al2, 0.f);
    al3 = fmaxf(al3, 0.f) + NEG*fminf(al3, 0.f);
    float w0 = __expf(al0), w1 = __expf(al1), w2 = __expf(al2), w3 = __expf(al3);
    c0 += w0*__uint_as_float(v0.x << 16)         + w1*__uint_as_float(v1.x << 16)
        + w2*__uint_as_float(v2.x << 16)         + w3*__uint_as_float(v3.x << 16);
    c1 += w0*__uint_as_float(v0.x & 0xffff0000u) + w1*__uint_as_float(v1.x & 0xffff0000u)
        + w2*__uint_as_float(v2.x & 0xffff0000u) + w3*__uint_as_float(v3.x & 0xffff0000u);
    c2 += w0*__uint_as_float(v0.y << 16)         + w1*__uint_as_float(v1.y << 16)
        + w2*__uint_as_float(v2.y << 16)         + w3*__uint_as_float(v3.y << 16);
    c3 += w0*__uint_as_float(v0.y & 0xffff0000u) + w1*__uint_as_float(v1.y & 0xffff0000u)
        + w2*__uint_as_float(v2.y & 0xffff0000u) + w3*__uint_as_float(v3.y & 0xffff0000u);
    dB += (w0 + w1) + (w2 + w3);
  }
  for (; p < p1; p++){
    uint4 q0 = csr[p];
    uint2 v0 = *(const uint2*)(zb + (((u32)q0.x << 9) + lbB));
    float al = __uint_as_float((q0.z << sh) & 0xffff0000u) + advB;
    al = fmaxf(al, 0.f) + NEG*fminf(al, 0.f);
    float w0 = __expf(al);
    c0 += w0*__uint_as_float(v0.x << 16);
    c1 += w0*__uint_as_float(v0.x & 0xffff0000u);
    c2 += w0*__uint_as_float(v0.y << 16);
    c3 += w0*__uint_as_float(v0.y & 0xffff0000u);
    dB += w0;
  }

  // combine: 0.25*(avg_hh + avg_{hh+2}) per lane, then merge hh groups
  float invA = (dA > 0.f) ? 0.25f / dA : 0.f;
  float invB = (dB > 0.f) ? 0.25f / dB : 0.f;
  float t0 = b0*invA + c0*invB;
  float t1 = b1*invA + c1*invB;
  float t2 = b2*invA + c2*invB;
  float t3 = b3*invA + c3*invB;
  t0 += __shfl_xor(t0, 16);
  t1 += __shfl_xor(t1, 16);
  t2 += __shfl_xor(t2, 16);
  t3 += __shfl_xor(t3, 16);
  if (hh == 0){                         // sl < 16: writer lanes
    const float* cv = cvec + c4*4;
    float4 o;
    o.x = fmaxf(t0 + cv[0], 0.f);
    o.y = fmaxf(t1 + cv[1], 0.f);
    o.z = fmaxf(t2 + cv[2], 0.f);
    o.w = fmaxf(t3 + cv[3], 0.f);
    *(float4*)(out + (size_t)n*64 + c4*4) = o;   // 16 lanes x 16B = 256B/node
  }
}

extern "C" void kernel_launch(void* const* d_in, const int* in_sizes, int n_in,
                              void* d_out, int out_size, void* d_ws, size_t ws_size,
                              hipStream_t stream){
  const float* x       = (const float*)d_in[0];
  const int*   eidx    = (const int*)d_in[1];
  const float* eattr   = (const float*)d_in[2];
  const float* qraw    = (const float*)d_in[3];
  const float* ns      = (const float*)d_in[4];
  const float* Wg      = (const float*)d_in[5];
  const float* att_src = (const float*)d_in[6];
  const float* att_dst = (const float*)d_in[7];
  const float* W_edge  = (const float*)d_in[8];
  const float* att_edge= (const float*)d_in[9];
  const float* b_gat   = (const float*)d_in[10];
  const float* Wq1     = (const float*)d_in[11];
  const float* bq1     = (const float*)d_in[12];
  const float* Wq2     = (const float*)d_in[13];
  const float* bq2     = (const float*)d_in[14];
  const float* W_c     = (const float*)d_in[15];
  const float* b_c     = (const float*)d_in[16];
  float* out = (float*)d_out;

  char* ws = (char*)d_ws;
  __hip_bfloat16* zs = (__hip_bfloat16*)ws;              // 0          (25,600,000)
  uint4* csr      = (uint4*)(ws + 25600000);             // 25.6M..38.4M (12.8MB)
  u32* deg8       = (u32*)(ws + 25600000);               // ALIAS: dead before csr written
  u32* offs8      = (u32*)(ws + 38400000);               // 1,600,064
  float* a_src    = (float*)(ws + 41600064);             //   800,000
  float* a_dst    = (float*)(ws + 42400064);             //   800,000
  unsigned short* rank = (unsigned short*)(ws + 43200064); // 1,600,000
  u32* bsum       = (u32*)(ws + 44800064);               //     4,096
  unsigned short* WzB = (unsigned short*)(ws + 44804160); //    65,536
  uint2* avp      = (uint2*)(ws + 44869696);             //     4,096
  float* Wt       = (float*)(ws + 44873792);             //       256
  float* cvec     = (float*)(ws + 44874048);             //       256

  k_pre_all<<<130+NZB,  256, 0, stream>>>(Wg, W_c, W_edge, att_edge, b_c, ns, b_gat,
                                          att_src, att_dst, WzB, Wt, cvec, avp, deg8);
  k_main   <<<NGB+NDB,  256, 0, stream>>>(x, WzB, avp, eidx + EE, zs, a_src, a_dst,
                                          deg8, rank);
  k_scan1  <<<NSB2,    1024, 0, stream>>>(deg8, offs8, bsum);
  k_scan2  <<<NSB2,    1024, 0, stream>>>(offs8, bsum);
  k_edge   <<<3125,     256, 0, stream>>>(qraw, eattr, eidx, Wq1, bq1, Wq2, bq2, Wt,
                                          a_src, offs8, rank, csr);
  k_agg    <<<6250,     256, 0, stream>>>(zs, csr, offs8, a_dst, cvec, out);
}

// Round 17
// 155.434 us; speedup vs baseline: 1.0651x; 1.0651x over previous
//
#include <hip/hip_runtime.h>
#include <hip/hip_bf16.h>

#define NN 50000
#define EE 800000
#define NEG 0.2f
#define NSH 8            // shards
#define NS (NN*NSH)      // scan length: (node, shard) pairs = 400000
#define NSB2 98          // scan blocks: ceil(NS/4096)
#define NZB 98           // deg-zero blocks in k_pre_all
#define NGB 1563         // gemm blocks: ceil(NN/32)
#define NDB 782          // deg blocks:  ceil(EE/1024)

using u32 = unsigned int;
typedef short short4v __attribute__((ext_vector_type(4)));
typedef float f32x4 __attribute__((ext_vector_type(4)));
typedef unsigned int u32x4 __attribute__((ext_vector_type(4)));

__device__ __forceinline__ unsigned short f2bf(float f){
  u32 b = __float_as_uint(f);
  b += 0x7FFFu + ((b >> 16) & 1u);        // RNE; inputs finite
  return (unsigned short)(b >> 16);
}

// ---- K0: merged precompute + deg8 zeroing (unchanged from R15) ----
__global__ __launch_bounds__(256) void k_pre_all(
        const float* __restrict__ Wg, const float* __restrict__ W_c,
        const float* __restrict__ W_edge, const float* __restrict__ att_edge,
        const float* __restrict__ b_c, const float* __restrict__ ns,
        const float* __restrict__ b_gat,
        const float* __restrict__ att_src, const float* __restrict__ att_dst,
        unsigned short* __restrict__ WzB, float* __restrict__ Wt,
        float* __restrict__ cvec, uint2* __restrict__ avp,
        u32* __restrict__ deg8){
  int bid = blockIdx.x, tid = threadIdx.x;
  if (bid < 128){
    __shared__ float sWg[256];
    __shared__ float sWc[64*64];
    sWg[tid] = Wg[bid*256 + tid];
    for (int i = tid; i < 4096; i += 256) sWc[i] = W_c[i];
    __syncthreads();
    int h = tid >> 6, j = tid & 63;
    float s = 0.f;
    #pragma unroll 8
    for (int c = 0; c < 64; c++) s += sWg[h*64 + c] * sWc[c*64 + j];
    int t = tid >> 4, lr = tid & 15;
    int ks = bid >> 4, lg = (bid >> 2) & 3, q = bid & 3;
    int l = lg*16 + lr;
    WzB[(((t*8 + ks)*64 + l) << 2) + q] = f2bf(s);
  } else if (bid == 128){
    if (tid < 64){
      int d = tid >> 2, h = tid & 3;
      float s = 0.f;
      for (int c = 0; c < 64; c++) s += W_edge[d*256 + h*64 + c] * att_edge[h*64 + c];
      Wt[d*4 + h] = s;
    } else if (tid < 128){
      int j = tid - 64;
      float s = b_c[j];
      for (int d = 0; d < 16; d++) s += ns[d >> 1] * W_c[(64 + d)*64 + j];
      for (int c = 0; c < 64; c++) s += b_gat[c] * W_c[c*64 + j];
      cvec[j] = s;
    }
  } else if (bid == 129){
    __shared__ float sav2[1024];       // [k][o] o: 0-3 src, 4-7 dst
    for (int i = tid; i < 1024; i += 256){
      int k = i >> 3, o = i & 7, h = o & 3;
      const float* att = (o < 4) ? att_src : att_dst;
      float s = 0.f;
      for (int c = 0; c < 64; c++) s += Wg[k*256 + h*64 + c] * att[h*64 + c];
      sav2[i] = s;
    }
    __syncthreads();
    if (tid < 64){
      int l = tid, lg = l >> 4, lr = l & 15;
      for (int ks = 0; ks < 8; ks++){
        unsigned int h0, h1, h2, h3;
        int kb = ks*16 + lg*4;
        h0 = (lr < 8) ? f2bf(sav2[(kb+0)*8 + lr]) : 0u;
        h1 = (lr < 8) ? f2bf(sav2[(kb+1)*8 + lr]) : 0u;
        h2 = (lr < 8) ? f2bf(sav2[(kb+2)*8 + lr]) : 0u;
        h3 = (lr < 8) ? f2bf(sav2[(kb+3)*8 + lr]) : 0u;
        uint2 u; u.x = h0 | (h1 << 16); u.y = h2 | (h3 << 16);
        avp[ks*64 + l] = u;
      }
    }
  } else {
    u32x4 z = {0u,0u,0u,0u};
    int slot0 = ((bid - 130)*256 + tid)*4;
    #pragma unroll
    for (int i = 0; i < 4; i++){
      int slot = slot0 + i;
      if (slot*4 < NS) *(u32x4*)(deg8 + slot*4) = z;
    }
  }
}

// ---- K1: heterogeneous main kernel; deg blocks also compute the edge MLP ----
__global__ __launch_bounds__(256) void k_main(const float* __restrict__ x,
        const unsigned short* __restrict__ WzB, const uint2* __restrict__ avp,
        const int* __restrict__ dsts,
        const float* __restrict__ qraw, const float* __restrict__ eattr,
        const float* __restrict__ Wq1, const float* __restrict__ bq1,
        const float* __restrict__ Wq2, const float* __restrict__ bq2,
        const float* __restrict__ Wt,
        __hip_bfloat16* __restrict__ zs,
        float* __restrict__ a_src, float* __restrict__ a_dst,
        u32* __restrict__ deg8, unsigned short* __restrict__ rank,
        uint2* __restrict__ aeb, int do_mlp){
  __shared__ alignas(16) char ldsu[17408];
  int tid = threadIdx.x;
  int bid = blockIdx.x;

  if ((bid % 3) == 1){
    // ---- deg histogram + (optional) per-edge MLP -> aeb ----
    float* swq = (float*)ldsu;                // [248] weight cache
    if (tid < 248){
      float v;
      if (tid < 32)       v = Wq1[tid];
      else if (tid < 40)  v = bq1[tid-32];
      else if (tid < 168) v = Wq2[tid-40];
      else if (tid < 184) v = bq2[tid-168];
      else                v = Wt[tid-184];
      swq[tid] = v;
    }
    __syncthreads();
    const float* sWq1 = swq;
    const float* sbq1 = swq + 32;
    const float* sWq2 = swq + 40;
    const float* sbq2 = swq + 168;
    const float* sWt  = swq + 184;

    int g = bid / 3;                          // 0..781
    int gi = g*256 + tid;                     // group of 4 edges (atomics)
    if (gi*4 < EE){
      int shard = g & (NSH-1);
      int4 d4 = *(const int4*)(dsts + (size_t)gi*4);
      u32 r0 = atomicAdd(&deg8[((size_t)(u32)d4.x << 3) | shard], 1u);
      u32 r1 = atomicAdd(&deg8[((size_t)(u32)d4.y << 3) | shard], 1u);
      u32 r2 = atomicAdd(&deg8[((size_t)(u32)d4.z << 3) | shard], 1u);
      u32 r3 = atomicAdd(&deg8[((size_t)(u32)d4.w << 3) | shard], 1u);
      uint2 pk;
      pk.x = (r0 & 0xffffu) | (r1 << 16);
      pk.y = (r2 & 0xffffu) | (r3 << 16);
      *(uint2*)(rank + (size_t)gi*4) = pk;
    }
    if (do_mlp){
      // strided edges for coalescing: e = g*1024 + k*256 + tid
      #pragma unroll
      for (int k = 0; k < 4; k++){
        int e = g*1024 + k*256 + tid;
        if (e >= EE) break;
        float4 qr = *(const float4*)(qraw + (size_t)e*4);
        float t1[8];
        #pragma unroll
        for (int j = 0; j < 8; j++){
          float s = sbq1[j] + qr.x*sWq1[j] + qr.y*sWq1[8+j] + qr.z*sWq1[16+j] + qr.w*sWq1[24+j];
          t1[j] = fmaxf(s, 0.f);
        }
        float ae[4] = {0.f,0.f,0.f,0.f};
        const float* ea = eattr + (size_t)e*16;
        #pragma unroll
        for (int d = 0; d < 16; d++){
          float q = sbq2[d];
          #pragma unroll
          for (int j = 0; j < 8; j++) q += t1[j]*sWq2[j*16 + d];
          float v = ea[d] + q;
          #pragma unroll
          for (int h = 0; h < 4; h++) ae[h] += v * sWt[d*4 + h];
        }
        uint2 u;
        u.x = (u32)f2bf(ae[0]) | ((u32)f2bf(ae[1]) << 16);
        u.y = (u32)f2bf(ae[2]) | ((u32)f2bf(ae[3]) << 16);
        aeb[e] = u;
      }
    }
    return;
  }

  int gb = bid - (bid + 2)/3;
  int w = tid >> 6, l = tid & 63;
  int lr = l & 15, lg = l >> 4;
  int rw = w >> 1, ch = w & 1;
  int nb = gb*32;
  int n0 = nb + rw*16;

  float* xsl = (float*)ldsu;
  __hip_bfloat16* ztp = (__hip_bfloat16*)ldsu;

  {
    float4 stg[4];
    #pragma unroll
    for (int i = 0; i < 4; i++){
      int s = w*256 + i*64 + l;
      int r = s >> 5, c = s & 31;
      int row = nb + r; if (row >= NN) row = NN - 1;
      stg[i] = *(const float4*)(x + (size_t)row*128 + c*4);
    }
    #pragma unroll
    for (int i = 0; i < 4; i++){
      int s = w*256 + i*64 + l;
      *(float4*)(xsl + s*4) = stg[i];
    }
  }
  __syncthreads();

  short4v afr[8];
  #pragma unroll
  for (int ks = 0; ks < 8; ks++){
    float4 xa = *(const float4*)(xsl + ((rw*16 + lr)*128 + ks*16 + lg*4));
    short4v a;
    a[0] = (short)f2bf(xa.x); a[1] = (short)f2bf(xa.y);
    a[2] = (short)f2bf(xa.z); a[3] = (short)f2bf(xa.w);
    afr[ks] = a;
  }
  if (ch == 0){
    f32x4 cad = {0.f, 0.f, 0.f, 0.f};
    #pragma unroll
    for (int ks = 0; ks < 8; ks++){
      short4v b = __builtin_bit_cast(short4v, avp[ks*64 + l]);
      cad = __builtin_amdgcn_mfma_f32_16x16x16bf16_1k(afr[ks], b, cad, 0, 0, 0);
    }
    #pragma unroll
    for (int r = 0; r < 4; r++){
      int n = n0 + lg*4 + r;
      if (n < NN){
        if (lr < 4)      a_src[(size_t)n*4 + lr]       = cad[r];
        else if (lr < 8) a_dst[(size_t)n*4 + (lr - 4)] = cad[r];
      }
    }
  }
  __syncthreads();

  #pragma unroll 4
  for (int t8 = 0; t8 < 8; t8++){
    int t = ch*8 + t8;
    f32x4 c = {0.f, 0.f, 0.f, 0.f};
    #pragma unroll
    for (int ks = 0; ks < 8; ks++){
      short4v b = *(const short4v*)(WzB + (((t*8 + ks)*64 + l) << 2));
      c = __builtin_amdgcn_mfma_f32_16x16x16bf16_1k(afr[ks], b, c, 0, 0, 0);
    }
    #pragma unroll
    for (int r = 0; r < 4; r++)
      ztp[((w*16) + lg*4 + r)*136 + t8*16 + lr] = __float2bfloat16(c[r]);
  }
  #pragma unroll
  for (int i = 0; i < 4; i++){
    int f = i*64 + l;
    int row = f >> 4, c16 = f & 15;
    int n = n0 + row;
    if (n < NN)
      *(uint4*)(zs + (size_t)n*256 + ch*128 + c16*8) = *(const uint4*)&ztp[(w*16 + row)*136 + c16*8];
  }
}

// ---- K3a/K3b: scans (unchanged from R15) ----
__global__ __launch_bounds__(1024) void k_scan1(const u32* __restrict__ deg8,
                                                u32* __restrict__ offs8, u32* __restrict__ bsum){
  __shared__ u32 sd[1024];
  int t = threadIdx.x;
  size_t base = (size_t)blockIdx.x*4096 + (size_t)t*4;
  u32x4 v = {0u,0u,0u,0u};
  if (base < NS) v = *(const u32x4*)(deg8 + base);
  u32 o1 = v.x, o2 = o1 + v.y, o3 = o2 + v.z;
  u32 tsum = o3 + v.w;
  sd[t] = tsum; __syncthreads();
  for (int off = 1; off < 1024; off <<= 1){
    u32 u = (t >= off) ? sd[t-off] : 0u;
    __syncthreads();
    sd[t] += u;
    __syncthreads();
  }
  u32 excl = sd[t] - tsum;
  if (base < NS){
    u32x4 o = {excl, excl + o1, excl + o2, excl + o3};
    *(u32x4*)(offs8 + base) = o;
  }
  if (t == 1023) bsum[blockIdx.x] = sd[1023];
}

__global__ __launch_bounds__(1024) void k_scan2(u32* __restrict__ offs8,
                                                const u32* __restrict__ bsum){
  __shared__ u32 sd[1024];
  int b = blockIdx.x, t = threadIdx.x;
  sd[t] = (t < b) ? bsum[t] : 0u;
  __syncthreads();
  #pragma unroll
  for (int off = 512; off; off >>= 1){
    if (t < off) sd[t] += sd[t + off];
    __syncthreads();
  }
  u32 p = sd[0];
  size_t base = (size_t)b*4096 + (size_t)t*4;
  if (base < NS){
    u32x4 o = *(u32x4*)(offs8 + base);
    o.x += p; o.y += p; o.z += p; o.w += p;
    *(u32x4*)(offs8 + base) = o;
  }
  if (b == 0 && t == 0) offs8[NS] = EE;
}

// ---- K4 fast: assemble CSR from precomputed aeb (no MLP) ----
__global__ __launch_bounds__(256) void k_edge_f(const int* __restrict__ eidx,
        const unsigned short* __restrict__ rank, const uint2* __restrict__ aeb,
        const float* __restrict__ a_src, const u32* __restrict__ offs8,
        uint4* __restrict__ csr){
  int e = blockIdx.x*256 + threadIdx.x;
  if (e >= EE) return;
  int shard = (blockIdx.x >> 2) & (NSH-1);
  int src = eidx[e], dst = eidx[EE + e];
  u32 rk = (u32)rank[e];
  uint2 ae2 = aeb[e];
  float4 as4 = *(const float4*)(a_src + (size_t)src*4);
  u32 base = offs8[((size_t)(u32)dst << 3) | shard];
  float ae0 = __uint_as_float(ae2.x << 16);
  float ae1 = __uint_as_float(ae2.x & 0xffff0000u);
  float ae2v = __uint_as_float(ae2.y << 16);
  float ae3 = __uint_as_float(ae2.y & 0xffff0000u);
  u32 pk0 = (u32)f2bf(as4.x + ae0);
  u32 pk1 = (u32)f2bf(as4.y + ae1);
  u32 pk2 = (u32)f2bf(as4.z + ae2v);
  u32 pk3 = (u32)f2bf(as4.w + ae3);
  uint4 q;
  q.x = (u32)src;
  q.y = pk0 | (pk1 << 16);
  q.z = pk2 | (pk3 << 16);
  q.w = 0u;
  csr[base + rk] = q;
}

// ---- K4 slow (fallback when ws too small): full MLP (R15 form) ----
__global__ __launch_bounds__(256) void k_edge_s(const float* __restrict__ qraw,
        const float* __restrict__ eattr, const int* __restrict__ eidx,
        const float* __restrict__ Wq1, const float* __restrict__ bq1,
        const float* __restrict__ Wq2, const float* __restrict__ bq2,
        const float* __restrict__ Wt,
        const float* __restrict__ a_src,
        const u32* __restrict__ offs8, const unsigned short* __restrict__ rank,
        uint4* __restrict__ csr){
  __shared__ float sWq1[32], sbq1[8], sWq2[128], sbq2[16], sWt[64];
  int tid = threadIdx.x;
  if (tid < 32) sWq1[tid] = Wq1[tid];
  else if (tid < 40)  sbq1[tid-32]  = bq1[tid-32];
  else if (tid < 168) sWq2[tid-40]  = Wq2[tid-40];
  else if (tid < 184) sbq2[tid-168] = bq2[tid-168];
  else if (tid < 248) sWt[tid-184]  = Wt[tid-184];
  __syncthreads();
  int e = blockIdx.x*256 + tid;
  if (e >= EE) return;
  int shard = (blockIdx.x >> 2) & (NSH-1);

  int src = eidx[e], dst = eidx[EE + e];
  u32 rk = (u32)rank[e];
  float4 qr = *(const float4*)(qraw + (size_t)e*4);
  float4 as4 = *(const float4*)(a_src + (size_t)src*4);
  u32 base = offs8[((size_t)(u32)dst << 3) | shard];

  float t1[8];
  #pragma unroll
  for (int j = 0; j < 8; j++){
    float s = sbq1[j] + qr.x*sWq1[j] + qr.y*sWq1[8+j] + qr.z*sWq1[16+j] + qr.w*sWq1[24+j];
    t1[j] = fmaxf(s, 0.f);
  }
  float ae[4] = {0.f,0.f,0.f,0.f};
  const float* ea = eattr + (size_t)e*16;
  #pragma unroll
  for (int d = 0; d < 16; d++){
    float q = sbq2[d];
    #pragma unroll
    for (int j = 0; j < 8; j++) q += t1[j]*sWq2[j*16 + d];
    float v = ea[d] + q;
    #pragma unroll
    for (int h = 0; h < 4; h++) ae[h] += v * sWt[d*4 + h];
  }
  u32 pk0 = (u32)f2bf(as4.x + ae[0]);
  u32 pk1 = (u32)f2bf(as4.y + ae[1]);
  u32 pk2 = (u32)f2bf(as4.z + ae[2]);
  u32 pk3 = (u32)f2bf(as4.w + ae[3]);
  uint4 q;
  q.x = (u32)src;
  q.y = pk0 | (pk1 << 16);
  q.z = pk2 | (pk3 << 16);
  q.w = 0u;
  csr[base + rk] = q;
}

// ---- K5: aggregation (exact R15 form: 2 nodes/wave, 16B/lane, 4x unroll) ----
__global__ __launch_bounds__(256) void k_agg(const __hip_bfloat16* __restrict__ zs,
        const uint4* __restrict__ csr, const u32* __restrict__ offs8,
        const float* __restrict__ a_dst,
        const float* __restrict__ cvec, float* __restrict__ out){
  int tid = threadIdx.x;
  int w = tid >> 6, lane = tid & 63;
  int half = lane >> 5, sl = lane & 31;
  int n = blockIdx.x*8 + w*2 + half;    // grid = NN/8 exactly
  int h = sl >> 3, c8 = sl & 7;
  u32 p0 = offs8[(size_t)n << 3], p1 = offs8[((size_t)n << 3) + 8];
  float adv = a_dst[((size_t)n << 2) + h];
  int sh = (h & 1) ? 0 : 16;
  u32 lb = (u32)(h*128 + c8*16);
  const char* zb = (const char*)zs;
  float d = 0.f;
  float a0=0.f,a1=0.f,a2=0.f,a3=0.f,a4=0.f,a5=0.f,a6=0.f,a7=0.f;
  u32 p = p0;
  for (; p + 4 <= p1; p += 4){
    uint4 q0 = csr[p+0], q1 = csr[p+1], q2 = csr[p+2], q3 = csr[p+3];
    u32 s0 = q0.x, s1 = q1.x, s2 = q2.x, s3 = q3.x;
    u32 w0p = (h < 2) ? q0.y : q0.z,  w1p = (h < 2) ? q1.y : q1.z;
    u32 w2p = (h < 2) ? q2.y : q2.z,  w3p = (h < 2) ? q3.y : q3.z;
    uint4 v0 = *(const uint4*)(zb + ((s0 << 9) + lb));
    uint4 v1 = *(const uint4*)(zb + ((s1 << 9) + lb));
    uint4 v2 = *(const uint4*)(zb + ((s2 << 9) + lb));
    uint4 v3 = *(const uint4*)(zb + ((s3 << 9) + lb));
    float al0 = __uint_as_float((w0p << sh) & 0xffff0000u) + adv;
    float al1 = __uint_as_float((w1p << sh) & 0xffff0000u) + adv;
    float al2 = __uint_as_float((w2p << sh) & 0xffff0000u) + adv;
    float al3 = __uint_as_float((w3p << sh) & 0xffff0000u) + adv;
    al0 = fmaxf(al0, 0.f) + NEG*fminf(al0, 0.f);
    al1 = fmaxf(al1, 0.f) + NEG*fminf(al1, 0.f);
    al2 = fmaxf(al2, 0.f) + NEG*fminf(al2, 0.f);
    al3 = fmaxf(al3, 0.f) + NEG*fminf(al3, 0.f);
    float w0 = __expf(al0), w1 = __expf(al1), w2 = __expf(al2), w3 = __expf(al3);
    a0 += w0*__uint_as_float(v0.x << 16)         + w1*__uint_as_float(v1.x << 16)
        + w2*__uint_as_float(v2.x << 16)         + w3*__uint_as_float(v3.x << 16);
    a1 += w0*__uint_as_float(v0.x & 0xffff0000u) + w1*__uint_as_float(v1.x & 0xffff0000u)
        + w2*__uint_as_float(v2.x & 0xffff0000u) + w3*__uint_as_float(v3.x & 0xffff0000u);
    a2 += w0*__uint_as_float(v0.y << 16)         + w1*__uint_as_float(v1.y << 16)
        + w2*__uint_as_float(v2.y << 16)         + w3*__uint_as_float(v3.y << 16);
    a3 += w0*__uint_as_float(v0.y & 0xffff0000u) + w1*__uint_as_float(v1.y & 0xffff0000u)
        + w2*__uint_as_float(v2.y & 0xffff0000u) + w3*__uint_as_float(v3.y & 0xffff0000u);
    a4 += w0*__uint_as_float(v0.z << 16)         + w1*__uint_as_float(v1.z << 16)
        + w2*__uint_as_float(v2.z << 16)         + w3*__uint_as_float(v3.z << 16);
    a5 += w0*__uint_as_float(v0.z & 0xffff0000u) + w1*__uint_as_float(v1.z & 0xffff0000u)
        + w2*__uint_as_float(v2.z & 0xffff0000u) + w3*__uint_as_float(v3.z & 0xffff0000u);
    a6 += w0*__uint_as_float(v0.w << 16)         + w1*__uint_as_float(v1.w << 16)
        + w2*__uint_as_float(v2.w << 16)         + w3*__uint_as_float(v3.w << 16);
    a7 += w0*__uint_as_float(v0.w & 0xffff0000u) + w1*__uint_as_float(v1.w & 0xffff0000u)
        + w2*__uint_as_float(v2.w & 0xffff0000u) + w3*__uint_as_float(v3.w & 0xffff0000u);
    d  += (w0 + w1) + (w2 + w3);
  }
  for (; p < p1; p++){
    uint4 q0 = csr[p];
    u32 wp = (h < 2) ? q0.y : q0.z;
    float al = __uint_as_float((wp << sh) & 0xffff0000u) + adv;
    al = fmaxf(al, 0.f) + NEG*fminf(al, 0.f);
    float w0 = __expf(al);
    uint4 v0 = *(const uint4*)(zb + ((q0.x << 9) + lb));
    a0 += w0*__uint_as_float(v0.x << 16);
    a1 += w0*__uint_as_float(v0.x & 0xffff0000u);
    a2 += w0*__uint_as_float(v0.y << 16);
    a3 += w0*__uint_as_float(v0.y & 0xffff0000u);
    a4 += w0*__uint_as_float(v0.z << 16);
    a5 += w0*__uint_as_float(v0.z & 0xffff0000u);
    a6 += w0*__uint_as_float(v0.w << 16);
    a7 += w0*__uint_as_float(v0.w & 0xffff0000u);
    d  += w0;
  }
  float inv = (d > 0.f) ? 0.25f / d : 0.f;
  a0 *= inv; a1 *= inv; a2 *= inv; a3 *= inv;
  a4 *= inv; a5 *= inv; a6 *= inv; a7 *= inv;
  a0 += __shfl_xor(a0, 8);  a1 += __shfl_xor(a1, 8);
  a2 += __shfl_xor(a2, 8);  a3 += __shfl_xor(a3, 8);
  a4 += __shfl_xor(a4, 8);  a5 += __shfl_xor(a5, 8);
  a6 += __shfl_xor(a6, 8);  a7 += __shfl_xor(a7, 8);
  a0 += __shfl_xor(a0, 16); a1 += __shfl_xor(a1, 16);
  a2 += __shfl_xor(a2, 16); a3 += __shfl_xor(a3, 16);
  a4 += __shfl_xor(a4, 16); a5 += __shfl_xor(a5, 16);
  a6 += __shfl_xor(a6, 16); a7 += __shfl_xor(a7, 16);
  if (h == 0){
    const float* cv = cvec + c8*8;
    float4 o0, o1v;
    o0.x  = fmaxf(a0 + cv[0], 0.f);
    o0.y  = fmaxf(a1 + cv[1], 0.f);
    o0.z  = fmaxf(a2 + cv[2], 0.f);
    o0.w  = fmaxf(a3 + cv[3], 0.f);
    o1v.x = fmaxf(a4 + cv[4], 0.f);
    o1v.y = fmaxf(a5 + cv[5], 0.f);
    o1v.z = fmaxf(a6 + cv[6], 0.f);
    o1v.w = fmaxf(a7 + cv[7], 0.f);
    float* op = out + (size_t)n*64 + c8*8;
    *(float4*)op = o0;
    *(float4*)(op + 4) = o1v;
  }
}

extern "C" void kernel_launch(void* const* d_in, const int* in_sizes, int n_in,
                              void* d_out, int out_size, void* d_ws, size_t ws_size,
                              hipStream_t stream){
  const float* x       = (const float*)d_in[0];
  const int*   eidx    = (const int*)d_in[1];
  const float* eattr   = (const float*)d_in[2];
  const float* qraw    = (const float*)d_in[3];
  const float* ns      = (const float*)d_in[4];
  const float* Wg      = (const float*)d_in[5];
  const float* att_src = (const float*)d_in[6];
  const float* att_dst = (const float*)d_in[7];
  const float* W_edge  = (const float*)d_in[8];
  const float* att_edge= (const float*)d_in[9];
  const float* b_gat   = (const float*)d_in[10];
  const float* Wq1     = (const float*)d_in[11];
  const float* bq1     = (const float*)d_in[12];
  const float* Wq2     = (const float*)d_in[13];
  const float* bq2     = (const float*)d_in[14];
  const float* W_c     = (const float*)d_in[15];
  const float* b_c     = (const float*)d_in[16];
  float* out = (float*)d_out;

  char* ws = (char*)d_ws;
  __hip_bfloat16* zs = (__hip_bfloat16*)ws;              // 0          (25,600,000)
  uint4* csr      = (uint4*)(ws + 25600000);             // 25.6M..38.4M (12.8MB)
  u32* deg8       = (u32*)(ws + 25600000);               // ALIAS: dead before csr written
  u32* offs8      = (u32*)(ws + 38400000);               // 1,600,064
  float* a_src    = (float*)(ws + 41600064);             //   800,000
  float* a_dst    = (float*)(ws + 42400064);             //   800,000
  unsigned short* rank = (unsigned short*)(ws + 43200064); // 1,600,000
  u32* bsum       = (u32*)(ws + 44800064);               //     4,096
  unsigned short* WzB = (unsigned short*)(ws + 44804160); //    65,536
  uint2* avp      = (uint2*)(ws + 44869696);             //     4,096
  float* Wt       = (float*)(ws + 44873792);             //       256
  float* cvec     = (float*)(ws + 44874048);             //       256
  uint2* aeb      = (uint2*)(ws + 44874304);             // 6,400,000 (if ws allows)
  int big = (ws_size >= (size_t)44874304 + 6400000) ? 1 : 0;

  k_pre_all<<<130+NZB,  256, 0, stream>>>(Wg, W_c, W_edge, att_edge, b_c, ns, b_gat,
                                          att_src, att_dst, WzB, Wt, cvec, avp, deg8);
  k_main   <<<NGB+NDB,  256, 0, stream>>>(x, WzB, avp, eidx + EE, qraw, eattr,
                                          Wq1, bq1, Wq2, bq2, Wt,
                                          zs, a_src, a_dst, deg8, rank, aeb, big);
  k_scan1  <<<NSB2,    1024, 0, stream>>>(deg8, offs8, bsum);
  k_scan2  <<<NSB2,    1024, 0, stream>>>(offs8, bsum);
  if (big){
    k_edge_f<<<3125,    256, 0, stream>>>(eidx, rank, aeb, a_src, offs8, csr);
  } else {
    k_edge_s<<<3125,    256, 0, stream>>>(qraw, eattr, eidx, Wq1, bq1, Wq2, bq2, Wt,
                                          a_src, offs8, rank, csr);
  }
  k_agg    <<<6250,     256, 0, stream>>>(zs, csr, offs8, a_dst, cvec, out);
}

// Round 18
// 148.094 us; speedup vs baseline: 1.1179x; 1.0496x over previous
//
#include <hip/hip_runtime.h>
#include <hip/hip_bf16.h>

#define NN 50000
#define EE 800000
#define NEG 0.2f
#define NSH 8            // shards
#define NS (NN*NSH)      // scan length: (node, shard) pairs = 400000
#define NSB2 98          // scan blocks: ceil(NS/4096)
#define NZB 98           // deg-zero blocks in k_pre_all
#define NGB 1563         // gemm blocks: ceil(NN/32)
#define NDB2 3125        // deg/MLP blocks: EE/256
#define NMB (NGB+NDB2)   // k_main grid = 4688

using u32 = unsigned int;
typedef short short4v __attribute__((ext_vector_type(4)));
typedef float f32x4 __attribute__((ext_vector_type(4)));
typedef unsigned int u32x4 __attribute__((ext_vector_type(4)));

__device__ __forceinline__ unsigned short f2bf(float f){
  u32 b = __float_as_uint(f);
  b += 0x7FFFu + ((b >> 16) & 1u);        // RNE; inputs finite
  return (unsigned short)(b >> 16);
}

// ---- K0: merged precompute + deg8 zeroing (unchanged from R15/R17) ----
__global__ __launch_bounds__(256) void k_pre_all(
        const float* __restrict__ Wg, const float* __restrict__ W_c,
        const float* __restrict__ W_edge, const float* __restrict__ att_edge,
        const float* __restrict__ b_c, const float* __restrict__ ns,
        const float* __restrict__ b_gat,
        const float* __restrict__ att_src, const float* __restrict__ att_dst,
        unsigned short* __restrict__ WzB, float* __restrict__ Wt,
        float* __restrict__ cvec, uint2* __restrict__ avp,
        u32* __restrict__ deg8){
  int bid = blockIdx.x, tid = threadIdx.x;
  if (bid < 128){
    __shared__ float sWg[256];
    __shared__ float sWc[64*64];
    sWg[tid] = Wg[bid*256 + tid];
    for (int i = tid; i < 4096; i += 256) sWc[i] = W_c[i];
    __syncthreads();
    int h = tid >> 6, j = tid & 63;
    float s = 0.f;
    #pragma unroll 8
    for (int c = 0; c < 64; c++) s += sWg[h*64 + c] * sWc[c*64 + j];
    int t = tid >> 4, lr = tid & 15;
    int ks = bid >> 4, lg = (bid >> 2) & 3, q = bid & 3;
    int l = lg*16 + lr;
    WzB[(((t*8 + ks)*64 + l) << 2) + q] = f2bf(s);
  } else if (bid == 128){
    if (tid < 64){
      int d = tid >> 2, h = tid & 3;
      float s = 0.f;
      for (int c = 0; c < 64; c++) s += W_edge[d*256 + h*64 + c] * att_edge[h*64 + c];
      Wt[d*4 + h] = s;
    } else if (tid < 128){
      int j = tid - 64;
      float s = b_c[j];
      for (int d = 0; d < 16; d++) s += ns[d >> 1] * W_c[(64 + d)*64 + j];
      for (int c = 0; c < 64; c++) s += b_gat[c] * W_c[c*64 + j];
      cvec[j] = s;
    }
  } else if (bid == 129){
    __shared__ float sav2[1024];       // [k][o] o: 0-3 src, 4-7 dst
    for (int i = tid; i < 1024; i += 256){
      int k = i >> 3, o = i & 7, h = o & 3;
      const float* att = (o < 4) ? att_src : att_dst;
      float s = 0.f;
      for (int c = 0; c < 64; c++) s += Wg[k*256 + h*64 + c] * att[h*64 + c];
      sav2[i] = s;
    }
    __syncthreads();
    if (tid < 64){
      int l = tid, lg = l >> 4, lr = l & 15;
      for (int ks = 0; ks < 8; ks++){
        unsigned int h0, h1, h2, h3;
        int kb = ks*16 + lg*4;
        h0 = (lr < 8) ? f2bf(sav2[(kb+0)*8 + lr]) : 0u;
        h1 = (lr < 8) ? f2bf(sav2[(kb+1)*8 + lr]) : 0u;
        h2 = (lr < 8) ? f2bf(sav2[(kb+2)*8 + lr]) : 0u;
        h3 = (lr < 8) ? f2bf(sav2[(kb+3)*8 + lr]) : 0u;
        uint2 u; u.x = h0 | (h1 << 16); u.y = h2 | (h3 << 16);
        avp[ks*64 + l] = u;
      }
    }
  } else {
    u32x4 z = {0u,0u,0u,0u};
    int slot0 = ((bid - 130)*256 + tid)*4;
    #pragma unroll
    for (int i = 0; i < 4; i++){
      int slot = slot0 + i;
      if (slot*4 < NS) *(u32x4*)(deg8 + slot*4) = z;
    }
  }
}

// ---- K1: heterogeneous main kernel ----
// bid%3==0 (1563 blocks): MFMA GEMM (32 rows).
// else     (3125 blocks): 256-edge deg histogram + per-edge MLP -> aeb.
//   Fine granularity: 1 MLP iteration/thread, no serial loop -> short blocks,
//   good tail packing; atomics issue first, MLP hides their latency.
__global__ __launch_bounds__(256) void k_main(const float* __restrict__ x,
        const unsigned short* __restrict__ WzB, const uint2* __restrict__ avp,
        const int* __restrict__ dsts,
        const float* __restrict__ qraw, const float* __restrict__ eattr,
        const float* __restrict__ Wq1, const float* __restrict__ bq1,
        const float* __restrict__ Wq2, const float* __restrict__ bq2,
        const float* __restrict__ Wt,
        __hip_bfloat16* __restrict__ zs,
        float* __restrict__ a_src, float* __restrict__ a_dst,
        u32* __restrict__ deg8, unsigned short* __restrict__ rank,
        uint2* __restrict__ aeb, int do_mlp){
  __shared__ alignas(16) char ldsu[17408];
  int tid = threadIdx.x;
  int bid = blockIdx.x;
  int m3 = bid % 3;

  if (m3 != 0){
    // ---- deg histogram + per-edge MLP -> aeb (256 edges) ----
    float* swq = (float*)ldsu;                // [248] weight cache
    if (tid < 248){
      float v;
      if (tid < 32)       v = Wq1[tid];
      else if (tid < 40)  v = bq1[tid-32];
      else if (tid < 168) v = Wq2[tid-40];
      else if (tid < 184) v = bq2[tid-168];
      else                v = Wt[tid-184];
      swq[tid] = v;
    }
    __syncthreads();
    const float* sWq1 = swq;
    const float* sbq1 = swq + 32;
    const float* sWq2 = swq + 40;
    const float* sbq2 = swq + 168;
    const float* sWt  = swq + 184;

    int g = 2*(bid/3) + (m3 - 1);             // 0..3124, bijective
    // atomics first (threads 0-63, 4 edges each via int4)
    if (tid < 64){
      int gi = g*64 + tid;
      int shard = (g >> 2) & (NSH-1);         // == (e>>10)&7, uniform per block
      int4 d4 = *(const int4*)(dsts + (size_t)gi*4);
      u32 r0 = atomicAdd(&deg8[((size_t)(u32)d4.x << 3) | shard], 1u);
      u32 r1 = atomicAdd(&deg8[((size_t)(u32)d4.y << 3) | shard], 1u);
      u32 r2 = atomicAdd(&deg8[((size_t)(u32)d4.z << 3) | shard], 1u);
      u32 r3 = atomicAdd(&deg8[((size_t)(u32)d4.w << 3) | shard], 1u);
      uint2 pk;
      pk.x = (r0 & 0xffffu) | (r1 << 16);
      pk.y = (r2 & 0xffffu) | (r3 << 16);
      *(uint2*)(rank + (size_t)gi*4) = pk;
    }
    if (do_mlp){
      int e = g*256 + tid;                    // < EE always (EE = 3125*256)
      float4 qr = *(const float4*)(qraw + (size_t)e*4);
      float t1[8];
      #pragma unroll
      for (int j = 0; j < 8; j++){
        float s = sbq1[j] + qr.x*sWq1[j] + qr.y*sWq1[8+j] + qr.z*sWq1[16+j] + qr.w*sWq1[24+j];
        t1[j] = fmaxf(s, 0.f);
      }
      float ae[4] = {0.f,0.f,0.f,0.f};
      const float* ea = eattr + (size_t)e*16;
      #pragma unroll
      for (int d = 0; d < 16; d++){
        float q = sbq2[d];
        #pragma unroll
        for (int j = 0; j < 8; j++) q += t1[j]*sWq2[j*16 + d];
        float v = ea[d] + q;
        #pragma unroll
        for (int h = 0; h < 4; h++) ae[h] += v * sWt[d*4 + h];
      }
      uint2 u;
      u.x = (u32)f2bf(ae[0]) | ((u32)f2bf(ae[1]) << 16);
      u.y = (u32)f2bf(ae[2]) | ((u32)f2bf(ae[3]) << 16);
      aeb[e] = u;
    }
    return;
  }

  int gb = bid / 3;                           // gemm id 0..1562
  int w = tid >> 6, l = tid & 63;
  int lr = l & 15, lg = l >> 4;
  int rw = w >> 1, ch = w & 1;
  int nb = gb*32;
  int n0 = nb + rw*16;

  float* xsl = (float*)ldsu;
  __hip_bfloat16* ztp = (__hip_bfloat16*)ldsu;

  {
    float4 stg[4];
    #pragma unroll
    for (int i = 0; i < 4; i++){
      int s = w*256 + i*64 + l;
      int r = s >> 5, c = s & 31;
      int row = nb + r; if (row >= NN) row = NN - 1;
      stg[i] = *(const float4*)(x + (size_t)row*128 + c*4);
    }
    #pragma unroll
    for (int i = 0; i < 4; i++){
      int s = w*256 + i*64 + l;
      *(float4*)(xsl + s*4) = stg[i];
    }
  }
  __syncthreads();

  short4v afr[8];
  #pragma unroll
  for (int ks = 0; ks < 8; ks++){
    float4 xa = *(const float4*)(xsl + ((rw*16 + lr)*128 + ks*16 + lg*4));
    short4v a;
    a[0] = (short)f2bf(xa.x); a[1] = (short)f2bf(xa.y);
    a[2] = (short)f2bf(xa.z); a[3] = (short)f2bf(xa.w);
    afr[ks] = a;
  }
  if (ch == 0){
    f32x4 cad = {0.f, 0.f, 0.f, 0.f};
    #pragma unroll
    for (int ks = 0; ks < 8; ks++){
      short4v b = __builtin_bit_cast(short4v, avp[ks*64 + l]);
      cad = __builtin_amdgcn_mfma_f32_16x16x16bf16_1k(afr[ks], b, cad, 0, 0, 0);
    }
    #pragma unroll
    for (int r = 0; r < 4; r++){
      int n = n0 + lg*4 + r;
      if (n < NN){
        if (lr < 4)      a_src[(size_t)n*4 + lr]       = cad[r];
        else if (lr < 8) a_dst[(size_t)n*4 + (lr - 4)] = cad[r];
      }
    }
  }
  __syncthreads();

  #pragma unroll 4
  for (int t8 = 0; t8 < 8; t8++){
    int t = ch*8 + t8;
    f32x4 c = {0.f, 0.f, 0.f, 0.f};
    #pragma unroll
    for (int ks = 0; ks < 8; ks++){
      short4v b = *(const short4v*)(WzB + (((t*8 + ks)*64 + l) << 2));
      c = __builtin_amdgcn_mfma_f32_16x16x16bf16_1k(afr[ks], b, c, 0, 0, 0);
    }
    #pragma unroll
    for (int r = 0; r < 4; r++)
      ztp[((w*16) + lg*4 + r)*136 + t8*16 + lr] = __float2bfloat16(c[r]);
  }
  #pragma unroll
  for (int i = 0; i < 4; i++){
    int f = i*64 + l;
    int row = f >> 4, c16 = f & 15;
    int n = n0 + row;
    if (n < NN)
      *(uint4*)(zs + (size_t)n*256 + ch*128 + c16*8) = *(const uint4*)&ztp[(w*16 + row)*136 + c16*8];
  }
}

// ---- K3a/K3b: scans (unchanged) ----
__global__ __launch_bounds__(1024) void k_scan1(const u32* __restrict__ deg8,
                                                u32* __restrict__ offs8, u32* __restrict__ bsum){
  __shared__ u32 sd[1024];
  int t = threadIdx.x;
  size_t base = (size_t)blockIdx.x*4096 + (size_t)t*4;
  u32x4 v = {0u,0u,0u,0u};
  if (base < NS) v = *(const u32x4*)(deg8 + base);
  u32 o1 = v.x, o2 = o1 + v.y, o3 = o2 + v.z;
  u32 tsum = o3 + v.w;
  sd[t] = tsum; __syncthreads();
  for (int off = 1; off < 1024; off <<= 1){
    u32 u = (t >= off) ? sd[t-off] : 0u;
    __syncthreads();
    sd[t] += u;
    __syncthreads();
  }
  u32 excl = sd[t] - tsum;
  if (base < NS){
    u32x4 o = {excl, excl + o1, excl + o2, excl + o3};
    *(u32x4*)(offs8 + base) = o;
  }
  if (t == 1023) bsum[blockIdx.x] = sd[1023];
}

__global__ __launch_bounds__(1024) void k_scan2(u32* __restrict__ offs8,
                                                const u32* __restrict__ bsum){
  __shared__ u32 sd[1024];
  int b = blockIdx.x, t = threadIdx.x;
  sd[t] = (t < b) ? bsum[t] : 0u;
  __syncthreads();
  #pragma unroll
  for (int off = 512; off; off >>= 1){
    if (t < off) sd[t] += sd[t + off];
    __syncthreads();
  }
  u32 p = sd[0];
  size_t base = (size_t)b*4096 + (size_t)t*4;
  if (base < NS){
    u32x4 o = *(u32x4*)(offs8 + base);
    o.x += p; o.y += p; o.z += p; o.w += p;
    *(u32x4*)(offs8 + base) = o;
  }
  if (b == 0 && t == 0) offs8[NS] = EE;
}

// ---- K4 fast: assemble CSR from precomputed aeb (no MLP) ----
__global__ __launch_bounds__(256) void k_edge_f(const int* __restrict__ eidx,
        const unsigned short* __restrict__ rank, const uint2* __restrict__ aeb,
        const float* __restrict__ a_src, const u32* __restrict__ offs8,
        uint4* __restrict__ csr){
  int e = blockIdx.x*256 + threadIdx.x;
  if (e >= EE) return;
  int shard = (blockIdx.x >> 2) & (NSH-1);
  int src = eidx[e], dst = eidx[EE + e];
  u32 rk = (u32)rank[e];
  uint2 ae2 = aeb[e];
  float4 as4 = *(const float4*)(a_src + (size_t)src*4);
  u32 base = offs8[((size_t)(u32)dst << 3) | shard];
  float ae0 = __uint_as_float(ae2.x << 16);
  float ae1 = __uint_as_float(ae2.x & 0xffff0000u);
  float ae2v = __uint_as_float(ae2.y << 16);
  float ae3 = __uint_as_float(ae2.y & 0xffff0000u);
  u32 pk0 = (u32)f2bf(as4.x + ae0);
  u32 pk1 = (u32)f2bf(as4.y + ae1);
  u32 pk2 = (u32)f2bf(as4.z + ae2v);
  u32 pk3 = (u32)f2bf(as4.w + ae3);
  uint4 q;
  q.x = (u32)src;
  q.y = pk0 | (pk1 << 16);
  q.z = pk2 | (pk3 << 16);
  q.w = 0u;
  csr[base + rk] = q;
}

// ---- K4 slow (fallback when ws too small): full MLP (R15 form) ----
__global__ __launch_bounds__(256) void k_edge_s(const float* __restrict__ qraw,
        const float* __restrict__ eattr, const int* __restrict__ eidx,
        const float* __restrict__ Wq1, const float* __restrict__ bq1,
        const float* __restrict__ Wq2, const float* __restrict__ bq2,
        const float* __restrict__ Wt,
        const float* __restrict__ a_src,
        const u32* __restrict__ offs8, const unsigned short* __restrict__ rank,
        uint4* __restrict__ csr){
  __shared__ float sWq1[32], sbq1[8], sWq2[128], sbq2[16], sWt[64];
  int tid = threadIdx.x;
  if (tid < 32) sWq1[tid] = Wq1[tid];
  else if (tid < 40)  sbq1[tid-32]  = bq1[tid-32];
  else if (tid < 168) sWq2[tid-40]  = Wq2[tid-40];
  else if (tid < 184) sbq2[tid-168] = bq2[tid-168];
  else if (tid < 248) sWt[tid-184]  = Wt[tid-184];
  __syncthreads();
  int e = blockIdx.x*256 + tid;
  if (e >= EE) return;
  int shard = (blockIdx.x >> 2) & (NSH-1);

  int src = eidx[e], dst = eidx[EE + e];
  u32 rk = (u32)rank[e];
  float4 qr = *(const float4*)(qraw + (size_t)e*4);
  float4 as4 = *(const float4*)(a_src + (size_t)src*4);
  u32 base = offs8[((size_t)(u32)dst << 3) | shard];

  float t1[8];
  #pragma unroll
  for (int j = 0; j < 8; j++){
    float s = sbq1[j] + qr.x*sWq1[j] + qr.y*sWq1[8+j] + qr.z*sWq1[16+j] + qr.w*sWq1[24+j];
    t1[j] = fmaxf(s, 0.f);
  }
  float ae[4] = {0.f,0.f,0.f,0.f};
  const float* ea = eattr + (size_t)e*16;
  #pragma unroll
  for (int d = 0; d < 16; d++){
    float q = sbq2[d];
    #pragma unroll
    for (int j = 0; j < 8; j++) q += t1[j]*sWq2[j*16 + d];
    float v = ea[d] + q;
    #pragma unroll
    for (int h = 0; h < 4; h++) ae[h] += v * sWt[d*4 + h];
  }
  u32 pk0 = (u32)f2bf(as4.x + ae[0]);
  u32 pk1 = (u32)f2bf(as4.y + ae[1]);
  u32 pk2 = (u32)f2bf(as4.z + ae[2]);
  u32 pk3 = (u32)f2bf(as4.w + ae[3]);
  uint4 q;
  q.x = (u32)src;
  q.y = pk0 | (pk1 << 16);
  q.z = pk2 | (pk3 << 16);
  q.w = 0u;
  csr[base + rk] = q;
}

// ---- K5: aggregation (exact R15 form: 2 nodes/wave, 16B/lane, 4x unroll) ----
__global__ __launch_bounds__(256) void k_agg(const __hip_bfloat16* __restrict__ zs,
        const uint4* __restrict__ csr, const u32* __restrict__ offs8,
        const float* __restrict__ a_dst,
        const float* __restrict__ cvec, float* __restrict__ out){
  int tid = threadIdx.x;
  int w = tid >> 6, lane = tid & 63;
  int half = lane >> 5, sl = lane & 31;
  int n = blockIdx.x*8 + w*2 + half;    // grid = NN/8 exactly
  int h = sl >> 3, c8 = sl & 7;
  u32 p0 = offs8[(size_t)n << 3], p1 = offs8[((size_t)n << 3) + 8];
  float adv = a_dst[((size_t)n << 2) + h];
  int sh = (h & 1) ? 0 : 16;
  u32 lb = (u32)(h*128 + c8*16);
  const char* zb = (const char*)zs;
  float d = 0.f;
  float a0=0.f,a1=0.f,a2=0.f,a3=0.f,a4=0.f,a5=0.f,a6=0.f,a7=0.f;
  u32 p = p0;
  for (; p + 4 <= p1; p += 4){
    uint4 q0 = csr[p+0], q1 = csr[p+1], q2 = csr[p+2], q3 = csr[p+3];
    u32 s0 = q0.x, s1 = q1.x, s2 = q2.x, s3 = q3.x;
    u32 w0p = (h < 2) ? q0.y : q0.z,  w1p = (h < 2) ? q1.y : q1.z;
    u32 w2p = (h < 2) ? q2.y : q2.z,  w3p = (h < 2) ? q3.y : q3.z;
    uint4 v0 = *(const uint4*)(zb + ((s0 << 9) + lb));
    uint4 v1 = *(const uint4*)(zb + ((s1 << 9) + lb));
    uint4 v2 = *(const uint4*)(zb + ((s2 << 9) + lb));
    uint4 v3 = *(const uint4*)(zb + ((s3 << 9) + lb));
    float al0 = __uint_as_float((w0p << sh) & 0xffff0000u) + adv;
    float al1 = __uint_as_float((w1p << sh) & 0xffff0000u) + adv;
    float al2 = __uint_as_float((w2p << sh) & 0xffff0000u) + adv;
    float al3 = __uint_as_float((w3p << sh) & 0xffff0000u) + adv;
    al0 = fmaxf(al0, 0.f) + NEG*fminf(al0, 0.f);
    al1 = fmaxf(al1, 0.f) + NEG*fminf(al1, 0.f);
    al2 = fmaxf(al2, 0.f) + NEG*fminf(al2, 0.f);
    al3 = fmaxf(al3, 0.f) + NEG*fminf(al3, 0.f);
    float w0 = __expf(al0), w1 = __expf(al1), w2 = __expf(al2), w3 = __expf(al3);
    a0 += w0*__uint_as_float(v0.x << 16)         + w1*__uint_as_float(v1.x << 16)
        + w2*__uint_as_float(v2.x << 16)         + w3*__uint_as_float(v3.x << 16);
    a1 += w0*__uint_as_float(v0.x & 0xffff0000u) + w1*__uint_as_float(v1.x & 0xffff0000u)
        + w2*__uint_as_float(v2.x & 0xffff0000u) + w3*__uint_as_float(v3.x & 0xffff0000u);
    a2 += w0*__uint_as_float(v0.y << 16)         + w1*__uint_as_float(v1.y << 16)
        + w2*__uint_as_float(v2.y << 16)         + w3*__uint_as_float(v3.y << 16);
    a3 += w0*__uint_as_float(v0.y & 0xffff0000u) + w1*__uint_as_float(v1.y & 0xffff0000u)
        + w2*__uint_as_float(v2.y & 0xffff0000u) + w3*__uint_as_float(v3.y & 0xffff0000u);
    a4 += w0*__uint_as_float(v0.z << 16)         + w1*__uint_as_float(v1.z << 16)
        + w2*__uint_as_float(v2.z << 16)         + w3*__uint_as_float(v3.z << 16);
    a5 += w0*__uint_as_float(v0.z & 0xffff0000u) + w1*__uint_as_float(v1.z & 0xffff0000u)
        + w2*__uint_as_float(v2.z & 0xffff0000u) + w3*__uint_as_float(v3.z & 0xffff0000u);
    a6 += w0*__uint_as_float(v0.w << 16)         + w1*__uint_as_float(v1.w << 16)
        + w2*__uint_as_float(v2.w << 16)         + w3*__uint_as_float(v3.w << 16);
    a7 += w0*__uint_as_float(v0.w & 0xffff0000u) + w1*__uint_as_float(v1.w & 0xffff0000u)
        + w2*__uint_as_float(v2.w & 0xffff0000u) + w3*__uint_as_float(v3.w & 0xffff0000u);
    d  += (w0 + w1) + (w2 + w3);
  }
  for (; p < p1; p++){
    uint4 q0 = csr[p];
    u32 wp = (h < 2) ? q0.y : q0.z;
    float al = __uint_as_float((wp << sh) & 0xffff0000u) + adv;
    al = fmaxf(al, 0.f) + NEG*fminf(al, 0.f);
    float w0 = __expf(al);
    uint4 v0 = *(const uint4*)(zb + ((q0.x << 9) + lb));
    a0 += w0*__uint_as_float(v0.x << 16);
    a1 += w0*__uint_as_float(v0.x & 0xffff0000u);
    a2 += w0*__uint_as_float(v0.y << 16);
    a3 += w0*__uint_as_float(v0.y & 0xffff0000u);
    a4 += w0*__uint_as_float(v0.z << 16);
    a5 += w0*__uint_as_float(v0.z & 0xffff0000u);
    a6 += w0*__uint_as_float(v0.w << 16);
    a7 += w0*__uint_as_float(v0.w & 0xffff0000u);
    d  += w0;
  }
  float inv = (d > 0.f) ? 0.25f / d : 0.f;
  a0 *= inv; a1 *= inv; a2 *= inv; a3 *= inv;
  a4 *= inv; a5 *= inv; a6 *= inv; a7 *= inv;
  a0 += __shfl_xor(a0, 8);  a1 += __shfl_xor(a1, 8);
  a2 += __shfl_xor(a2, 8);  a3 += __shfl_xor(a3, 8);
  a4 += __shfl_xor(a4, 8);  a5 += __shfl_xor(a5, 8);
  a6 += __shfl_xor(a6, 8);  a7 += __shfl_xor(a7, 8);
  a0 += __shfl_xor(a0, 16); a1 += __shfl_xor(a1, 16);
  a2 += __shfl_xor(a2, 16); a3 += __shfl_xor(a3, 16);
  a4 += __shfl_xor(a4, 16); a5 += __shfl_xor(a5, 16);
  a6 += __shfl_xor(a6, 16); a7 += __shfl_xor(a7, 16);
  if (h == 0){
    const float* cv = cvec + c8*8;
    float4 o0, o1v;
    o0.x  = fmaxf(a0 + cv[0], 0.f);
    o0.y  = fmaxf(a1 + cv[1], 0.f);
    o0.z  = fmaxf(a2 + cv[2], 0.f);
    o0.w  = fmaxf(a3 + cv[3], 0.f);
    o1v.x = fmaxf(a4 + cv[4], 0.f);
    o1v.y = fmaxf(a5 + cv[5], 0.f);
    o1v.z = fmaxf(a6 + cv[6], 0.f);
    o1v.w = fmaxf(a7 + cv[7], 0.f);
    float* op = out + (size_t)n*64 + c8*8;
    *(float4*)op = o0;
    *(float4*)(op + 4) = o1v;
  }
}

extern "C" void kernel_launch(void* const* d_in, const int* in_sizes, int n_in,
                              void* d_out, int out_size, void* d_ws, size_t ws_size,
                              hipStream_t stream){
  const float* x       = (const float*)d_in[0];
  const int*   eidx    = (const int*)d_in[1];
  const float* eattr   = (const float*)d_in[2];
  const float* qraw    = (const float*)d_in[3];
  const float* ns      = (const float*)d_in[4];
  const float* Wg      = (const float*)d_in[5];
  const float* att_src = (const float*)d_in[6];
  const float* att_dst = (const float*)d_in[7];
  const float* W_edge  = (const float*)d_in[8];
  const float* att_edge= (const float*)d_in[9];
  const float* b_gat   = (const float*)d_in[10];
  const float* Wq1     = (const float*)d_in[11];
  const float* bq1     = (const float*)d_in[12];
  const float* Wq2     = (const float*)d_in[13];
  const float* bq2     = (const float*)d_in[14];
  const float* W_c     = (const float*)d_in[15];
  const float* b_c     = (const float*)d_in[16];
  float* out = (float*)d_out;

  char* ws = (char*)d_ws;
  __hip_bfloat16* zs = (__hip_bfloat16*)ws;              // 0          (25,600,000)
  uint4* csr      = (uint4*)(ws + 25600000);             // 25.6M..38.4M (12.8MB)
  u32* deg8       = (u32*)(ws + 25600000);               // ALIAS: dead before csr written
  u32* offs8      = (u32*)(ws + 38400000);               // 1,600,064
  float* a_src    = (float*)(ws + 41600064);             //   800,000
  float* a_dst    = (float*)(ws + 42400064);             //   800,000
  unsigned short* rank = (unsigned short*)(ws + 43200064); // 1,600,000
  u32* bsum       = (u32*)(ws + 44800064);               //     4,096
  unsigned short* WzB = (unsigned short*)(ws + 44804160); //    65,536
  uint2* avp      = (uint2*)(ws + 44869696);             //     4,096
  float* Wt       = (float*)(ws + 44873792);             //       256
  float* cvec     = (float*)(ws + 44874048);             //       256
  uint2* aeb      = (uint2*)(ws + 44874304);             // 6,400,000 (if ws allows)
  int big = (ws_size >= (size_t)44874304 + 6400000) ? 1 : 0;

  k_pre_all<<<130+NZB,  256, 0, stream>>>(Wg, W_c, W_edge, att_edge, b_c, ns, b_gat,
                                          att_src, att_dst, WzB, Wt, cvec, avp, deg8);
  k_main   <<<NMB,      256, 0, stream>>>(x, WzB, avp, eidx + EE, qraw, eattr,
                                          Wq1, bq1, Wq2, bq2, Wt,
                                          zs, a_src, a_dst, deg8, rank, aeb, big);
  k_scan1  <<<NSB2,    1024, 0, stream>>>(deg8, offs8, bsum);
  k_scan2  <<<NSB2,    1024, 0, stream>>>(offs8, bsum);
  if (big){
    k_edge_f<<<3125,    256, 0, stream>>>(eidx, rank, aeb, a_src, offs8, csr);
  } else {
    k_edge_s<<<3125,    256, 0, stream>>>(qraw, eattr, eidx, Wq1, bq1, Wq2, bq2, Wt,
                                          a_src, offs8, rank, csr);
  }
  k_agg    <<<6250,     256, 0, stream>>>(zs, csr, offs8, a_dst, cvec, out);
}

// Round 19
// 147.828 us; speedup vs baseline: 1.1199x; 1.0018x over previous
//
#include <hip/hip_runtime.h>
#include <hip/hip_bf16.h>

#define NN 50000
#define EE 800000
#define NEG 0.2f
#define NSH 8            // shards
#define NS (NN*NSH)      // scan length: (node, shard) pairs = 400000
#define NSB2 98          // scan blocks: ceil(NS/4096)
#define NZB 98           // deg-zero blocks in k_pre_all
#define NGB 1563         // gemm blocks: ceil(NN/32)
#define NDB2 3125        // deg/MLP blocks: EE/256
#define NMB (NGB+NDB2)   // k_main grid = 4688

using u32 = unsigned int;
typedef short short4v __attribute__((ext_vector_type(4)));
typedef float f32x4 __attribute__((ext_vector_type(4)));
typedef unsigned int u32x4 __attribute__((ext_vector_type(4)));

__device__ __forceinline__ unsigned short f2bf(float f){
  u32 b = __float_as_uint(f);
  b += 0x7FFFu + ((b >> 16) & 1u);        // RNE; inputs finite
  return (unsigned short)(b >> 16);
}

// ---- K0: merged precompute + deg8 zeroing (unchanged) ----
__global__ __launch_bounds__(256) void k_pre_all(
        const float* __restrict__ Wg, const float* __restrict__ W_c,
        const float* __restrict__ W_edge, const float* __restrict__ att_edge,
        const float* __restrict__ b_c, const float* __restrict__ ns,
        const float* __restrict__ b_gat,
        const float* __restrict__ att_src, const float* __restrict__ att_dst,
        unsigned short* __restrict__ WzB, float* __restrict__ Wt,
        float* __restrict__ cvec, uint2* __restrict__ avp,
        u32* __restrict__ deg8){
  int bid = blockIdx.x, tid = threadIdx.x;
  if (bid < 128){
    __shared__ float sWg[256];
    __shared__ float sWc[64*64];
    sWg[tid] = Wg[bid*256 + tid];
    for (int i = tid; i < 4096; i += 256) sWc[i] = W_c[i];
    __syncthreads();
    int h = tid >> 6, j = tid & 63;
    float s = 0.f;
    #pragma unroll 8
    for (int c = 0; c < 64; c++) s += sWg[h*64 + c] * sWc[c*64 + j];
    int t = tid >> 4, lr = tid & 15;
    int ks = bid >> 4, lg = (bid >> 2) & 3, q = bid & 3;
    int l = lg*16 + lr;
    WzB[(((t*8 + ks)*64 + l) << 2) + q] = f2bf(s);
  } else if (bid == 128){
    if (tid < 64){
      int d = tid >> 2, h = tid & 3;
      float s = 0.f;
      for (int c = 0; c < 64; c++) s += W_edge[d*256 + h*64 + c] * att_edge[h*64 + c];
      Wt[d*4 + h] = s;
    } else if (tid < 128){
      int j = tid - 64;
      float s = b_c[j];
      for (int d = 0; d < 16; d++) s += ns[d >> 1] * W_c[(64 + d)*64 + j];
      for (int c = 0; c < 64; c++) s += b_gat[c] * W_c[c*64 + j];
      cvec[j] = s;
    }
  } else if (bid == 129){
    __shared__ float sav2[1024];       // [k][o] o: 0-3 src, 4-7 dst
    for (int i = tid; i < 1024; i += 256){
      int k = i >> 3, o = i & 7, h = o & 3;
      const float* att = (o < 4) ? att_src : att_dst;
      float s = 0.f;
      for (int c = 0; c < 64; c++) s += Wg[k*256 + h*64 + c] * att[h*64 + c];
      sav2[i] = s;
    }
    __syncthreads();
    if (tid < 64){
      int l = tid, lg = l >> 4, lr = l & 15;
      for (int ks = 0; ks < 8; ks++){
        unsigned int h0, h1, h2, h3;
        int kb = ks*16 + lg*4;
        h0 = (lr < 8) ? f2bf(sav2[(kb+0)*8 + lr]) : 0u;
        h1 = (lr < 8) ? f2bf(sav2[(kb+1)*8 + lr]) : 0u;
        h2 = (lr < 8) ? f2bf(sav2[(kb+2)*8 + lr]) : 0u;
        h3 = (lr < 8) ? f2bf(sav2[(kb+3)*8 + lr]) : 0u;
        uint2 u; u.x = h0 | (h1 << 16); u.y = h2 | (h3 << 16);
        avp[ks*64 + l] = u;
      }
    }
  } else {
    u32x4 z = {0u,0u,0u,0u};
    int slot0 = ((bid - 130)*256 + tid)*4;
    #pragma unroll
    for (int i = 0; i < 4; i++){
      int slot = slot0 + i;
      if (slot*4 < NS) *(u32x4*)(deg8 + slot*4) = z;
    }
  }
}

// ---- K1: heterogeneous main kernel ----
// bid%3==0 (1563 blocks): MFMA GEMM (32 rows).
// else     (3125 blocks): 256-edge deg histogram + per-edge MLP -> aeb.
//   1 atomic/thread across ALL waves (each hides under its own MLP);
//   eattr hoisted as 4x float4 before the compute chain.
__global__ __launch_bounds__(256) void k_main(const float* __restrict__ x,
        const unsigned short* __restrict__ WzB, const uint2* __restrict__ avp,
        const int* __restrict__ dsts,
        const float* __restrict__ qraw, const float* __restrict__ eattr,
        const float* __restrict__ Wq1, const float* __restrict__ bq1,
        const float* __restrict__ Wq2, const float* __restrict__ bq2,
        const float* __restrict__ Wt,
        __hip_bfloat16* __restrict__ zs,
        float* __restrict__ a_src, float* __restrict__ a_dst,
        u32* __restrict__ deg8, unsigned short* __restrict__ rank,
        uint2* __restrict__ aeb, int do_mlp){
  __shared__ alignas(16) char ldsu[17408];
  int tid = threadIdx.x;
  int bid = blockIdx.x;
  int m3 = bid % 3;

  if (m3 != 0){
    // ---- deg histogram + per-edge MLP -> aeb (256 edges, 1/thread) ----
    float* swq = (float*)ldsu;                // [248] weight cache
    if (tid < 248){
      float v;
      if (tid < 32)       v = Wq1[tid];
      else if (tid < 40)  v = bq1[tid-32];
      else if (tid < 168) v = Wq2[tid-40];
      else if (tid < 184) v = bq2[tid-168];
      else                v = Wt[tid-184];
      swq[tid] = v;
    }
    __syncthreads();
    const float* sWq1 = swq;
    const float* sbq1 = swq + 32;
    const float* sWq2 = swq + 40;
    const float* sbq2 = swq + 168;
    const float* sWt  = swq + 184;

    int g = 2*(bid/3) + (m3 - 1);             // 0..3124, bijective
    int e = g*256 + tid;                      // < EE always (EE = 3125*256)
    int shard = (g >> 2) & (NSH-1);           // == (e>>10)&7, uniform per block

    // one atomic per thread; every wave hides its RMW under the MLP below
    int dst = dsts[e];
    u32 rk = atomicAdd(&deg8[((size_t)(u32)dst << 3) | shard], 1u);

    if (do_mlp){
      // hoisted vector loads (issue before the dependent compute chain)
      float4 qr  = *(const float4*)(qraw + (size_t)e*4);
      const float* ea = eattr + (size_t)e*16;
      float4 ev0 = *(const float4*)(ea);
      float4 ev1 = *(const float4*)(ea + 4);
      float4 ev2 = *(const float4*)(ea + 8);
      float4 ev3 = *(const float4*)(ea + 12);
      float ev[16];
      ev[0]=ev0.x; ev[1]=ev0.y; ev[2]=ev0.z; ev[3]=ev0.w;
      ev[4]=ev1.x; ev[5]=ev1.y; ev[6]=ev1.z; ev[7]=ev1.w;
      ev[8]=ev2.x; ev[9]=ev2.y; ev[10]=ev2.z; ev[11]=ev2.w;
      ev[12]=ev3.x; ev[13]=ev3.y; ev[14]=ev3.z; ev[15]=ev3.w;

      float t1[8];
      #pragma unroll
      for (int j = 0; j < 8; j++){
        float s = sbq1[j] + qr.x*sWq1[j] + qr.y*sWq1[8+j] + qr.z*sWq1[16+j] + qr.w*sWq1[24+j];
        t1[j] = fmaxf(s, 0.f);
      }
      float ae[4] = {0.f,0.f,0.f,0.f};
      #pragma unroll
      for (int d = 0; d < 16; d++){
        float q = sbq2[d];
        #pragma unroll
        for (int j = 0; j < 8; j++) q += t1[j]*sWq2[j*16 + d];
        float v = ev[d] + q;
        #pragma unroll
        for (int h = 0; h < 4; h++) ae[h] += v * sWt[d*4 + h];
      }
      uint2 u;
      u.x = (u32)f2bf(ae[0]) | ((u32)f2bf(ae[1]) << 16);
      u.y = (u32)f2bf(ae[2]) | ((u32)f2bf(ae[3]) << 16);
      aeb[e] = u;
    }
    rank[e] = (unsigned short)rk;             // coalesced 2B/thread store
    return;
  }

  int gb = bid / 3;                           // gemm id 0..1562
  int w = tid >> 6, l = tid & 63;
  int lr = l & 15, lg = l >> 4;
  int rw = w >> 1, ch = w & 1;
  int nb = gb*32;
  int n0 = nb + rw*16;

  float* xsl = (float*)ldsu;
  __hip_bfloat16* ztp = (__hip_bfloat16*)ldsu;

  {
    float4 stg[4];
    #pragma unroll
    for (int i = 0; i < 4; i++){
      int s = w*256 + i*64 + l;
      int r = s >> 5, c = s & 31;
      int row = nb + r; if (row >= NN) row = NN - 1;
      stg[i] = *(const float4*)(x + (size_t)row*128 + c*4);
    }
    #pragma unroll
    for (int i = 0; i < 4; i++){
      int s = w*256 + i*64 + l;
      *(float4*)(xsl + s*4) = stg[i];
    }
  }
  __syncthreads();

  short4v afr[8];
  #pragma unroll
  for (int ks = 0; ks < 8; ks++){
    float4 xa = *(const float4*)(xsl + ((rw*16 + lr)*128 + ks*16 + lg*4));
    short4v a;
    a[0] = (short)f2bf(xa.x); a[1] = (short)f2bf(xa.y);
    a[2] = (short)f2bf(xa.z); a[3] = (short)f2bf(xa.w);
    afr[ks] = a;
  }
  if (ch == 0){
    f32x4 cad = {0.f, 0.f, 0.f, 0.f};
    #pragma unroll
    for (int ks = 0; ks < 8; ks++){
      short4v b = __builtin_bit_cast(short4v, avp[ks*64 + l]);
      cad = __builtin_amdgcn_mfma_f32_16x16x16bf16_1k(afr[ks], b, cad, 0, 0, 0);
    }
    #pragma unroll
    for (int r = 0; r < 4; r++){
      int n = n0 + lg*4 + r;
      if (n < NN){
        if (lr < 4)      a_src[(size_t)n*4 + lr]       = cad[r];
        else if (lr < 8) a_dst[(size_t)n*4 + (lr - 4)] = cad[r];
      }
    }
  }
  __syncthreads();

  #pragma unroll 4
  for (int t8 = 0; t8 < 8; t8++){
    int t = ch*8 + t8;
    f32x4 c = {0.f, 0.f, 0.f, 0.f};
    #pragma unroll
    for (int ks = 0; ks < 8; ks++){
      short4v b = *(const short4v*)(WzB + (((t*8 + ks)*64 + l) << 2));
      c = __builtin_amdgcn_mfma_f32_16x16x16bf16_1k(afr[ks], b, c, 0, 0, 0);
    }
    #pragma unroll
    for (int r = 0; r < 4; r++)
      ztp[((w*16) + lg*4 + r)*136 + t8*16 + lr] = __float2bfloat16(c[r]);
  }
  #pragma unroll
  for (int i = 0; i < 4; i++){
    int f = i*64 + l;
    int row = f >> 4, c16 = f & 15;
    int n = n0 + row;
    if (n < NN)
      *(uint4*)(zs + (size_t)n*256 + ch*128 + c16*8) = *(const uint4*)&ztp[(w*16 + row)*136 + c16*8];
  }
}

// ---- K3a/K3b: scans (unchanged) ----
__global__ __launch_bounds__(1024) void k_scan1(const u32* __restrict__ deg8,
                                                u32* __restrict__ offs8, u32* __restrict__ bsum){
  __shared__ u32 sd[1024];
  int t = threadIdx.x;
  size_t base = (size_t)blockIdx.x*4096 + (size_t)t*4;
  u32x4 v = {0u,0u,0u,0u};
  if (base < NS) v = *(const u32x4*)(deg8 + base);
  u32 o1 = v.x, o2 = o1 + v.y, o3 = o2 + v.z;
  u32 tsum = o3 + v.w;
  sd[t] = tsum; __syncthreads();
  for (int off = 1; off < 1024; off <<= 1){
    u32 u = (t >= off) ? sd[t-off] : 0u;
    __syncthreads();
    sd[t] += u;
    __syncthreads();
  }
  u32 excl = sd[t] - tsum;
  if (base < NS){
    u32x4 o = {excl, excl + o1, excl + o2, excl + o3};
    *(u32x4*)(offs8 + base) = o;
  }
  if (t == 1023) bsum[blockIdx.x] = sd[1023];
}

__global__ __launch_bounds__(1024) void k_scan2(u32* __restrict__ offs8,
                                                const u32* __restrict__ bsum){
  __shared__ u32 sd[1024];
  int b = blockIdx.x, t = threadIdx.x;
  sd[t] = (t < b) ? bsum[t] : 0u;
  __syncthreads();
  #pragma unroll
  for (int off = 512; off; off >>= 1){
    if (t < off) sd[t] += sd[t + off];
    __syncthreads();
  }
  u32 p = sd[0];
  size_t base = (size_t)b*4096 + (size_t)t*4;
  if (base < NS){
    u32x4 o = *(u32x4*)(offs8 + base);
    o.x += p; o.y += p; o.z += p; o.w += p;
    *(u32x4*)(offs8 + base) = o;
  }
  if (b == 0 && t == 0) offs8[NS] = EE;
}

// ---- K4 fast: assemble CSR from precomputed aeb (no MLP) ----
__global__ __launch_bounds__(256) void k_edge_f(const int* __restrict__ eidx,
        const unsigned short* __restrict__ rank, const uint2* __restrict__ aeb,
        const float* __restrict__ a_src, const u32* __restrict__ offs8,
        uint4* __restrict__ csr){
  int e = blockIdx.x*256 + threadIdx.x;
  if (e >= EE) return;
  int shard = (blockIdx.x >> 2) & (NSH-1);
  int src = eidx[e], dst = eidx[EE + e];
  u32 rk = (u32)rank[e];
  uint2 ae2 = aeb[e];
  float4 as4 = *(const float4*)(a_src + (size_t)src*4);
  u32 base = offs8[((size_t)(u32)dst << 3) | shard];
  float ae0 = __uint_as_float(ae2.x << 16);
  float ae1 = __uint_as_float(ae2.x & 0xffff0000u);
  float ae2v = __uint_as_float(ae2.y << 16);
  float ae3 = __uint_as_float(ae2.y & 0xffff0000u);
  u32 pk0 = (u32)f2bf(as4.x + ae0);
  u32 pk1 = (u32)f2bf(as4.y + ae1);
  u32 pk2 = (u32)f2bf(as4.z + ae2v);
  u32 pk3 = (u32)f2bf(as4.w + ae3);
  uint4 q;
  q.x = (u32)src;
  q.y = pk0 | (pk1 << 16);
  q.z = pk2 | (pk3 << 16);
  q.w = 0u;
  csr[base + rk] = q;
}

// ---- K4 slow (fallback when ws too small): full MLP (R15 form) ----
__global__ __launch_bounds__(256) void k_edge_s(const float* __restrict__ qraw,
        const float* __restrict__ eattr, const int* __restrict__ eidx,
        const float* __restrict__ Wq1, const float* __restrict__ bq1,
        const float* __restrict__ Wq2, const float* __restrict__ bq2,
        const float* __restrict__ Wt,
        const float* __restrict__ a_src,
        const u32* __restrict__ offs8, const unsigned short* __restrict__ rank,
        uint4* __restrict__ csr){
  __shared__ float sWq1[32], sbq1[8], sWq2[128], sbq2[16], sWt[64];
  int tid = threadIdx.x;
  if (tid < 32) sWq1[tid] = Wq1[tid];
  else if (tid < 40)  sbq1[tid-32]  = bq1[tid-32];
  else if (tid < 168) sWq2[tid-40]  = Wq2[tid-40];
  else if (tid < 184) sbq2[tid-168] = bq2[tid-168];
  else if (tid < 248) sWt[tid-184]  = Wt[tid-184];
  __syncthreads();
  int e = blockIdx.x*256 + tid;
  if (e >= EE) return;
  int shard = (blockIdx.x >> 2) & (NSH-1);

  int src = eidx[e], dst = eidx[EE + e];
  u32 rk = (u32)rank[e];
  float4 qr = *(const float4*)(qraw + (size_t)e*4);
  float4 as4 = *(const float4*)(a_src + (size_t)src*4);
  u32 base = offs8[((size_t)(u32)dst << 3) | shard];

  float t1[8];
  #pragma unroll
  for (int j = 0; j < 8; j++){
    float s = sbq1[j] + qr.x*sWq1[j] + qr.y*sWq1[8+j] + qr.z*sWq1[16+j] + qr.w*sWq1[24+j];
    t1[j] = fmaxf(s, 0.f);
  }
  float ae[4] = {0.f,0.f,0.f,0.f};
  const float* ea = eattr + (size_t)e*16;
  #pragma unroll
  for (int d = 0; d < 16; d++){
    float q = sbq2[d];
    #pragma unroll
    for (int j = 0; j < 8; j++) q += t1[j]*sWq2[j*16 + d];
    float v = ea[d] + q;
    #pragma unroll
    for (int h = 0; h < 4; h++) ae[h] += v * sWt[d*4 + h];
  }
  u32 pk0 = (u32)f2bf(as4.x + ae[0]);
  u32 pk1 = (u32)f2bf(as4.y + ae[1]);
  u32 pk2 = (u32)f2bf(as4.z + ae[2]);
  u32 pk3 = (u32)f2bf(as4.w + ae[3]);
  uint4 q;
  q.x = (u32)src;
  q.y = pk0 | (pk1 << 16);
  q.z = pk2 | (pk3 << 16);
  q.w = 0u;
  csr[base + rk] = q;
}

// ---- K5: aggregation (exact R15 form: 2 nodes/wave, 16B/lane, 4x unroll) ----
__global__ __launch_bounds__(256) void k_agg(const __hip_bfloat16* __restrict__ zs,
        const uint4* __restrict__ csr, const u32* __restrict__ offs8,
        const float* __restrict__ a_dst,
        const float* __restrict__ cvec, float* __restrict__ out){
  int tid = threadIdx.x;
  int w = tid >> 6, lane = tid & 63;
  int half = lane >> 5, sl = lane & 31;
  int n = blockIdx.x*8 + w*2 + half;    // grid = NN/8 exactly
  int h = sl >> 3, c8 = sl & 7;
  u32 p0 = offs8[(size_t)n << 3], p1 = offs8[((size_t)n << 3) + 8];
  float adv = a_dst[((size_t)n << 2) + h];
  int sh = (h & 1) ? 0 : 16;
  u32 lb = (u32)(h*128 + c8*16);
  const char* zb = (const char*)zs;
  float d = 0.f;
  float a0=0.f,a1=0.f,a2=0.f,a3=0.f,a4=0.f,a5=0.f,a6=0.f,a7=0.f;
  u32 p = p0;
  for (; p + 4 <= p1; p += 4){
    uint4 q0 = csr[p+0], q1 = csr[p+1], q2 = csr[p+2], q3 = csr[p+3];
    u32 s0 = q0.x, s1 = q1.x, s2 = q2.x, s3 = q3.x;
    u32 w0p = (h < 2) ? q0.y : q0.z,  w1p = (h < 2) ? q1.y : q1.z;
    u32 w2p = (h < 2) ? q2.y : q2.z,  w3p = (h < 2) ? q3.y : q3.z;
    uint4 v0 = *(const uint4*)(zb + ((s0 << 9) + lb));
    uint4 v1 = *(const uint4*)(zb + ((s1 << 9) + lb));
    uint4 v2 = *(const uint4*)(zb + ((s2 << 9) + lb));
    uint4 v3 = *(const uint4*)(zb + ((s3 << 9) + lb));
    float al0 = __uint_as_float((w0p << sh) & 0xffff0000u) + adv;
    float al1 = __uint_as_float((w1p << sh) & 0xffff0000u) + adv;
    float al2 = __uint_as_float((w2p << sh) & 0xffff0000u) + adv;
    float al3 = __uint_as_float((w3p << sh) & 0xffff0000u) + adv;
    al0 = fmaxf(al0, 0.f) + NEG*fminf(al0, 0.f);
    al1 = fmaxf(al1, 0.f) + NEG*fminf(al1, 0.f);
    al2 = fmaxf(al2, 0.f) + NEG*fminf(al2, 0.f);
    al3 = fmaxf(al3, 0.f) + NEG*fminf(al3, 0.f);
    float w0 = __expf(al0), w1 = __expf(al1), w2 = __expf(al2), w3 = __expf(al3);
    a0 += w0*__uint_as_float(v0.x << 16)         + w1*__uint_as_float(v1.x << 16)
        + w2*__uint_as_float(v2.x << 16)         + w3*__uint_as_float(v3.x << 16);
    a1 += w0*__uint_as_float(v0.x & 0xffff0000u) + w1*__uint_as_float(v1.x & 0xffff0000u)
        + w2*__uint_as_float(v2.x & 0xffff0000u) + w3*__uint_as_float(v3.x & 0xffff0000u);
    a2 += w0*__uint_as_float(v0.y << 16)         + w1*__uint_as_float(v1.y << 16)
        + w2*__uint_as_float(v2.y << 16)         + w3*__uint_as_float(v3.y << 16);
    a3 += w0*__uint_as_float(v0.y & 0xffff0000u) + w1*__uint_as_float(v1.y & 0xffff0000u)
        + w2*__uint_as_float(v2.y & 0xffff0000u) + w3*__uint_as_float(v3.y & 0xffff0000u);
    a4 += w0*__uint_as_float(v0.z << 16)         + w1*__uint_as_float(v1.z << 16)
        + w2*__uint_as_float(v2.z << 16)         + w3*__uint_as_float(v3.z << 16);
    a5 += w0*__uint_as_float(v0.z & 0xffff0000u) + w1*__uint_as_float(v1.z & 0xffff0000u)
        + w2*__uint_as_float(v2.z & 0xffff0000u) + w3*__uint_as_float(v3.z & 0xffff0000u);
    a6 += w0*__uint_as_float(v0.w << 16)         + w1*__uint_as_float(v1.w << 16)
        + w2*__uint_as_float(v2.w << 16)         + w3*__uint_as_float(v3.w << 16);
    a7 += w0*__uint_as_float(v0.w & 0xffff0000u) + w1*__uint_as_float(v1.w & 0xffff0000u)
        + w2*__uint_as_float(v2.w & 0xffff0000u) + w3*__uint_as_float(v3.w & 0xffff0000u);
    d  += (w0 + w1) + (w2 + w3);
  }
  for (; p < p1; p++){
    uint4 q0 = csr[p];
    u32 wp = (h < 2) ? q0.y : q0.z;
    float al = __uint_as_float((wp << sh) & 0xffff0000u) + adv;
    al = fmaxf(al, 0.f) + NEG*fminf(al, 0.f);
    float w0 = __expf(al);
    uint4 v0 = *(const uint4*)(zb + ((q0.x << 9) + lb));
    a0 += w0*__uint_as_float(v0.x << 16);
    a1 += w0*__uint_as_float(v0.x & 0xffff0000u);
    a2 += w0*__uint_as_float(v0.y << 16);
    a3 += w0*__uint_as_float(v0.y & 0xffff0000u);
    a4 += w0*__uint_as_float(v0.z << 16);
    a5 += w0*__uint_as_float(v0.z & 0xffff0000u);
    a6 += w0*__uint_as_float(v0.w << 16);
    a7 += w0*__uint_as_float(v0.w & 0xffff0000u);
    d  += w0;
  }
  float inv = (d > 0.f) ? 0.25f / d : 0.f;
  a0 *= inv; a1 *= inv; a2 *= inv; a3 *= inv;
  a4 *= inv; a5 *= inv; a6 *= inv; a7 *= inv;
  a0 += __shfl_xor(a0, 8);  a1 += __shfl_xor(a1, 8);
  a2 += __shfl_xor(a2, 8);  a3 += __shfl_xor(a3, 8);
  a4 += __shfl_xor(a4, 8);  a5 += __shfl_xor(a5, 8);
  a6 += __shfl_xor(a6, 8);  a7 += __shfl_xor(a7, 8);
  a0 += __shfl_xor(a0, 16); a1 += __shfl_xor(a1, 16);
  a2 += __shfl_xor(a2, 16); a3 += __shfl_xor(a3, 16);
  a4 += __shfl_xor(a4, 16); a5 += __shfl_xor(a5, 16);
  a6 += __shfl_xor(a6, 16); a7 += __shfl_xor(a7, 16);
  if (h == 0){
    const float* cv = cvec + c8*8;
    float4 o0, o1v;
    o0.x  = fmaxf(a0 + cv[0], 0.f);
    o0.y  = fmaxf(a1 + cv[1], 0.f);
    o0.z  = fmaxf(a2 + cv[2], 0.f);
    o0.w  = fmaxf(a3 + cv[3], 0.f);
    o1v.x = fmaxf(a4 + cv[4], 0.f);
    o1v.y = fmaxf(a5 + cv[5], 0.f);
    o1v.z = fmaxf(a6 + cv[6], 0.f);
    o1v.w = fmaxf(a7 + cv[7], 0.f);
    float* op = out + (size_t)n*64 + c8*8;
    *(float4*)op = o0;
    *(float4*)(op + 4) = o1v;
  }
}

extern "C" void kernel_launch(void* const* d_in, const int* in_sizes, int n_in,
                              void* d_out, int out_size, void* d_ws, size_t ws_size,
                              hipStream_t stream){
  const float* x       = (const float*)d_in[0];
  const int*   eidx    = (const int*)d_in[1];
  const float* eattr   = (const float*)d_in[2];
  const float* qraw    = (const float*)d_in[3];
  const float* ns      = (const float*)d_in[4];
  const float* Wg      = (const float*)d_in[5];
  const float* att_src = (const float*)d_in[6];
  const float* att_dst = (const float*)d_in[7];
  const float* W_edge  = (const float*)d_in[8];
  const float* att_edge= (const float*)d_in[9];
  const float* b_gat   = (const float*)d_in[10];
  const float* Wq1     = (const float*)d_in[11];
  const float* bq1     = (const float*)d_in[12];
  const float* Wq2     = (const float*)d_in[13];
  const float* bq2     = (const float*)d_in[14];
  const float* W_c     = (const float*)d_in[15];
  const float* b_c     = (const float*)d_in[16];
  float* out = (float*)d_out;

  char* ws = (char*)d_ws;
  __hip_bfloat16* zs = (__hip_bfloat16*)ws;              // 0          (25,600,000)
  uint4* csr      = (uint4*)(ws + 25600000);             // 25.6M..38.4M (12.8MB)
  u32* deg8       = (u32*)(ws + 25600000);               // ALIAS: dead before csr written
  u32* offs8      = (u32*)(ws + 38400000);               // 1,600,064
  float* a_src    = (float*)(ws + 41600064);             //   800,000
  float* a_dst    = (float*)(ws + 42400064);             //   800,000
  unsigned short* rank = (unsigned short*)(ws + 43200064); // 1,600,000
  u32* bsum       = (u32*)(ws + 44800064);               //     4,096
  unsigned short* WzB = (unsigned short*)(ws + 44804160); //    65,536
  uint2* avp      = (uint2*)(ws + 44869696);             //     4,096
  float* Wt       = (float*)(ws + 44873792);             //       256
  float* cvec     = (float*)(ws + 44874048);             //       256
  uint2* aeb      = (uint2*)(ws + 44874304);             // 6,400,000 (if ws allows)
  int big = (ws_size >= (size_t)44874304 + 6400000) ? 1 : 0;

  k_pre_all<<<130+NZB,  256, 0, stream>>>(Wg, W_c, W_edge, att_edge, b_c, ns, b_gat,
                                          att_src, att_dst, WzB, Wt, cvec, avp, deg8);
  k_main   <<<NMB,      256, 0, stream>>>(x, WzB, avp, eidx + EE, qraw, eattr,
                                          Wq1, bq1, Wq2, bq2, Wt,
                                          zs, a_src, a_dst, deg8, rank, aeb, big);
  k_scan1  <<<NSB2,    1024, 0, stream>>>(deg8, offs8, bsum);
  k_scan2  <<<NSB2,    1024, 0, stream>>>(offs8, bsum);
  if (big){
    k_edge_f<<<3125,    256, 0, stream>>>(eidx, rank, aeb, a_src, offs8, csr);
  } else {
    k_edge_s<<<3125,    256, 0, stream>>>(qraw, eattr, eidx, Wq1, bq1, Wq2, bq2, Wt,
                                          a_src, offs8, rank, csr);
  }
  k_agg    <<<6250,     256, 0, stream>>>(zs, csr, offs8, a_dst, cvec, out);
}

// Round 20
// 147.327 us; speedup vs baseline: 1.1237x; 1.0034x over previous
//
#include <hip/hip_runtime.h>
#include <hip/hip_bf16.h>

#define NN 50000
#define EE 800000
#define NEG 0.2f
#define NSH 8            // shards
#define NS (NN*NSH)      // scan length: (node, shard) pairs = 400000
#define NSB2 98          // scan blocks: ceil(NS/4096)
#define NZB 98           // deg-zero blocks in k_pre_all
#define NGB 1563         // gemm blocks: ceil(NN/32)
#define NDB2 3125        // deg/MLP blocks: EE/256
#define NMB (NGB+NDB2)   // k_main grid = 4688

using u32 = unsigned int;
typedef short short4v __attribute__((ext_vector_type(4)));
typedef float f32x4 __attribute__((ext_vector_type(4)));
typedef unsigned int u32x4 __attribute__((ext_vector_type(4)));

__device__ __forceinline__ unsigned short f2bf(float f){
  u32 b = __float_as_uint(f);
  b += 0x7FFFu + ((b >> 16) & 1u);        // RNE; inputs finite
  return (unsigned short)(b >> 16);
}

// ---- K0: merged precompute + deg8 zeroing (unchanged) ----
__global__ __launch_bounds__(256) void k_pre_all(
        const float* __restrict__ Wg, const float* __restrict__ W_c,
        const float* __restrict__ W_edge, const float* __restrict__ att_edge,
        const float* __restrict__ b_c, const float* __restrict__ ns,
        const float* __restrict__ b_gat,
        const float* __restrict__ att_src, const float* __restrict__ att_dst,
        unsigned short* __restrict__ WzB, float* __restrict__ Wt,
        float* __restrict__ cvec, uint2* __restrict__ avp,
        u32* __restrict__ deg8){
  int bid = blockIdx.x, tid = threadIdx.x;
  if (bid < 128){
    __shared__ float sWg[256];
    __shared__ float sWc[64*64];
    sWg[tid] = Wg[bid*256 + tid];
    for (int i = tid; i < 4096; i += 256) sWc[i] = W_c[i];
    __syncthreads();
    int h = tid >> 6, j = tid & 63;
    float s = 0.f;
    #pragma unroll 8
    for (int c = 0; c < 64; c++) s += sWg[h*64 + c] * sWc[c*64 + j];
    int t = tid >> 4, lr = tid & 15;
    int ks = bid >> 4, lg = (bid >> 2) & 3, q = bid & 3;
    int l = lg*16 + lr;
    WzB[(((t*8 + ks)*64 + l) << 2) + q] = f2bf(s);
  } else if (bid == 128){
    if (tid < 64){
      int d = tid >> 2, h = tid & 3;
      float s = 0.f;
      for (int c = 0; c < 64; c++) s += W_edge[d*256 + h*64 + c] * att_edge[h*64 + c];
      Wt[d*4 + h] = s;
    } else if (tid < 128){
      int j = tid - 64;
      float s = b_c[j];
      for (int d = 0; d < 16; d++) s += ns[d >> 1] * W_c[(64 + d)*64 + j];
      for (int c = 0; c < 64; c++) s += b_gat[c] * W_c[c*64 + j];
      cvec[j] = s;
    }
  } else if (bid == 129){
    __shared__ float sav2[1024];       // [k][o] o: 0-3 src, 4-7 dst
    for (int i = tid; i < 1024; i += 256){
      int k = i >> 3, o = i & 7, h = o & 3;
      const float* att = (o < 4) ? att_src : att_dst;
      float s = 0.f;
      for (int c = 0; c < 64; c++) s += Wg[k*256 + h*64 + c] * att[h*64 + c];
      sav2[i] = s;
    }
    __syncthreads();
    if (tid < 64){
      int l = tid, lg = l >> 4, lr = l & 15;
      for (int ks = 0; ks < 8; ks++){
        unsigned int h0, h1, h2, h3;
        int kb = ks*16 + lg*4;
        h0 = (lr < 8) ? f2bf(sav2[(kb+0)*8 + lr]) : 0u;
        h1 = (lr < 8) ? f2bf(sav2[(kb+1)*8 + lr]) : 0u;
        h2 = (lr < 8) ? f2bf(sav2[(kb+2)*8 + lr]) : 0u;
        h3 = (lr < 8) ? f2bf(sav2[(kb+3)*8 + lr]) : 0u;
        uint2 u; u.x = h0 | (h1 << 16); u.y = h2 | (h3 << 16);
        avp[ks*64 + l] = u;
      }
    }
  } else {
    u32x4 z = {0u,0u,0u,0u};
    int slot0 = ((bid - 130)*256 + tid)*4;
    #pragma unroll
    for (int i = 0; i < 4; i++){
      int slot = slot0 + i;
      if (slot*4 < NS) *(u32x4*)(deg8 + slot*4) = z;
    }
  }
}

// ---- K1: heterogeneous main kernel ----
// bid%3==0 (1563 blocks): MFMA GEMM (32 rows); x-panel stride 132 floats
//   -> A-frag ds_read bank-group = (lr+lg+4ks)%8: 8-way (the b128 floor),
//   was 16-way at stride 128.
// else     (3125 blocks): 256-edge deg histogram + per-edge MLP -> aeb.
__global__ __launch_bounds__(256) void k_main(const float* __restrict__ x,
        const unsigned short* __restrict__ WzB, const uint2* __restrict__ avp,
        const int* __restrict__ dsts,
        const float* __restrict__ qraw, const float* __restrict__ eattr,
        const float* __restrict__ Wq1, const float* __restrict__ bq1,
        const float* __restrict__ Wq2, const float* __restrict__ bq2,
        const float* __restrict__ Wt,
        __hip_bfloat16* __restrict__ zs,
        float* __restrict__ a_src, float* __restrict__ a_dst,
        u32* __restrict__ deg8, unsigned short* __restrict__ rank,
        uint2* __restrict__ aeb, int do_mlp){
  __shared__ alignas(16) char ldsu[17408];
  int tid = threadIdx.x;
  int bid = blockIdx.x;
  int m3 = bid % 3;

  if (m3 != 0){
    // ---- deg histogram + per-edge MLP -> aeb (256 edges, 1/thread) ----
    float* swq = (float*)ldsu;                // [248] weight cache
    if (tid < 248){
      float v;
      if (tid < 32)       v = Wq1[tid];
      else if (tid < 40)  v = bq1[tid-32];
      else if (tid < 168) v = Wq2[tid-40];
      else if (tid < 184) v = bq2[tid-168];
      else                v = Wt[tid-184];
      swq[tid] = v;
    }
    __syncthreads();
    const float* sWq1 = swq;
    const float* sbq1 = swq + 32;
    const float* sWq2 = swq + 40;
    const float* sbq2 = swq + 168;
    const float* sWt  = swq + 184;

    int g = 2*(bid/3) + (m3 - 1);             // 0..3124, bijective
    int e = g*256 + tid;                      // < EE always (EE = 3125*256)
    int shard = (g >> 2) & (NSH-1);           // == (e>>10)&7, uniform per block

    int dst = dsts[e];
    u32 rk = atomicAdd(&deg8[((size_t)(u32)dst << 3) | shard], 1u);

    if (do_mlp){
      float4 qr  = *(const float4*)(qraw + (size_t)e*4);
      const float* ea = eattr + (size_t)e*16;
      float4 ev0 = *(const float4*)(ea);
      float4 ev1 = *(const float4*)(ea + 4);
      float4 ev2 = *(const float4*)(ea + 8);
      float4 ev3 = *(const float4*)(ea + 12);
      float ev[16];
      ev[0]=ev0.x; ev[1]=ev0.y; ev[2]=ev0.z; ev[3]=ev0.w;
      ev[4]=ev1.x; ev[5]=ev1.y; ev[6]=ev1.z; ev[7]=ev1.w;
      ev[8]=ev2.x; ev[9]=ev2.y; ev[10]=ev2.z; ev[11]=ev2.w;
      ev[12]=ev3.x; ev[13]=ev3.y; ev[14]=ev3.z; ev[15]=ev3.w;

      float t1[8];
      #pragma unroll
      for (int j = 0; j < 8; j++){
        float s = sbq1[j] + qr.x*sWq1[j] + qr.y*sWq1[8+j] + qr.z*sWq1[16+j] + qr.w*sWq1[24+j];
        t1[j] = fmaxf(s, 0.f);
      }
      float ae[4] = {0.f,0.f,0.f,0.f};
      #pragma unroll
      for (int d = 0; d < 16; d++){
        float q = sbq2[d];
        #pragma unroll
        for (int j = 0; j < 8; j++) q += t1[j]*sWq2[j*16 + d];
        float v = ev[d] + q;
        #pragma unroll
        for (int h = 0; h < 4; h++) ae[h] += v * sWt[d*4 + h];
      }
      uint2 u;
      u.x = (u32)f2bf(ae[0]) | ((u32)f2bf(ae[1]) << 16);
      u.y = (u32)f2bf(ae[2]) | ((u32)f2bf(ae[3]) << 16);
      aeb[e] = u;
    }
    rank[e] = (unsigned short)rk;             // coalesced 2B/thread store
    return;
  }

  int gb = bid / 3;                           // gemm id 0..1562
  int w = tid >> 6, l = tid & 63;
  int lr = l & 15, lg = l >> 4;
  int rw = w >> 1, ch = w & 1;
  int nb = gb*32;
  int n0 = nb + rw*16;

  float* xsl = (float*)ldsu;                    // [32][132] padded fp32 panel
  __hip_bfloat16* ztp = (__hip_bfloat16*)ldsu;  // [4][16][136] out tile (after)

  {
    float4 stg[4];
    #pragma unroll
    for (int i = 0; i < 4; i++){
      int s = w*256 + i*64 + l;
      int r = s >> 5, c = s & 31;
      int row = nb + r; if (row >= NN) row = NN - 1;
      stg[i] = *(const float4*)(x + (size_t)row*128 + c*4);
    }
    #pragma unroll
    for (int i = 0; i < 4; i++){
      int s = w*256 + i*64 + l;
      int r = s >> 5, c = s & 31;
      *(float4*)(xsl + r*132 + c*4) = stg[i];   // padded stride: conflict-free
    }
  }
  __syncthreads();

  short4v afr[8];
  #pragma unroll
  for (int ks = 0; ks < 8; ks++){
    float4 xa = *(const float4*)(xsl + ((rw*16 + lr)*132 + ks*16 + lg*4));
    short4v a;
    a[0] = (short)f2bf(xa.x); a[1] = (short)f2bf(xa.y);
    a[2] = (short)f2bf(xa.z); a[3] = (short)f2bf(xa.w);
    afr[ks] = a;
  }
  if (ch == 0){
    f32x4 cad = {0.f, 0.f, 0.f, 0.f};
    #pragma unroll
    for (int ks = 0; ks < 8; ks++){
      short4v b = __builtin_bit_cast(short4v, avp[ks*64 + l]);
      cad = __builtin_amdgcn_mfma_f32_16x16x16bf16_1k(afr[ks], b, cad, 0, 0, 0);
    }
    #pragma unroll
    for (int r = 0; r < 4; r++){
      int n = n0 + lg*4 + r;
      if (n < NN){
        if (lr < 4)      a_src[(size_t)n*4 + lr]       = cad[r];
        else if (lr < 8) a_dst[(size_t)n*4 + (lr - 4)] = cad[r];
      }
    }
  }
  __syncthreads();

  #pragma unroll 4
  for (int t8 = 0; t8 < 8; t8++){
    int t = ch*8 + t8;
    f32x4 c = {0.f, 0.f, 0.f, 0.f};
    #pragma unroll
    for (int ks = 0; ks < 8; ks++){
      short4v b = *(const short4v*)(WzB + (((t*8 + ks)*64 + l) << 2));
      c = __builtin_amdgcn_mfma_f32_16x16x16bf16_1k(afr[ks], b, c, 0, 0, 0);
    }
    #pragma unroll
    for (int r = 0; r < 4; r++)
      ztp[((w*16) + lg*4 + r)*136 + t8*16 + lr] = __float2bfloat16(c[r]);
  }
  #pragma unroll
  for (int i = 0; i < 4; i++){
    int f = i*64 + l;
    int row = f >> 4, c16 = f & 15;
    int n = n0 + row;
    if (n < NN)
      *(uint4*)(zs + (size_t)n*256 + ch*128 + c16*8) = *(const uint4*)&ztp[(w*16 + row)*136 + c16*8];
  }
}

// ---- K3a/K3b: scans (unchanged) ----
__global__ __launch_bounds__(1024) void k_scan1(const u32* __restrict__ deg8,
                                                u32* __restrict__ offs8, u32* __restrict__ bsum){
  __shared__ u32 sd[1024];
  int t = threadIdx.x;
  size_t base = (size_t)blockIdx.x*4096 + (size_t)t*4;
  u32x4 v = {0u,0u,0u,0u};
  if (base < NS) v = *(const u32x4*)(deg8 + base);
  u32 o1 = v.x, o2 = o1 + v.y, o3 = o2 + v.z;
  u32 tsum = o3 + v.w;
  sd[t] = tsum; __syncthreads();
  for (int off = 1; off < 1024; off <<= 1){
    u32 u = (t >= off) ? sd[t-off] : 0u;
    __syncthreads();
    sd[t] += u;
    __syncthreads();
  }
  u32 excl = sd[t] - tsum;
  if (base < NS){
    u32x4 o = {excl, excl + o1, excl + o2, excl + o3};
    *(u32x4*)(offs8 + base) = o;
  }
  if (t == 1023) bsum[blockIdx.x] = sd[1023];
}

__global__ __launch_bounds__(1024) void k_scan2(u32* __restrict__ offs8,
                                                const u32* __restrict__ bsum){
  __shared__ u32 sd[1024];
  int b = blockIdx.x, t = threadIdx.x;
  sd[t] = (t < b) ? bsum[t] : 0u;
  __syncthreads();
  #pragma unroll
  for (int off = 512; off; off >>= 1){
    if (t < off) sd[t] += sd[t + off];
    __syncthreads();
  }
  u32 p = sd[0];
  size_t base = (size_t)b*4096 + (size_t)t*4;
  if (base < NS){
    u32x4 o = *(u32x4*)(offs8 + base);
    o.x += p; o.y += p; o.z += p; o.w += p;
    *(u32x4*)(offs8 + base) = o;
  }
  if (b == 0 && t == 0) offs8[NS] = EE;
}

// ---- K4 fast: assemble CSR from precomputed aeb (no MLP) ----
__global__ __launch_bounds__(256) void k_edge_f(const int* __restrict__ eidx,
        const unsigned short* __restrict__ rank, const uint2* __restrict__ aeb,
        const float* __restrict__ a_src, const u32* __restrict__ offs8,
        uint4* __restrict__ csr){
  int e = blockIdx.x*256 + threadIdx.x;
  if (e >= EE) return;
  int shard = (blockIdx.x >> 2) & (NSH-1);
  int src = eidx[e], dst = eidx[EE + e];
  u32 rk = (u32)rank[e];
  uint2 ae2 = aeb[e];
  float4 as4 = *(const float4*)(a_src + (size_t)src*4);
  u32 base = offs8[((size_t)(u32)dst << 3) | shard];
  float ae0 = __uint_as_float(ae2.x << 16);
  float ae1 = __uint_as_float(ae2.x & 0xffff0000u);
  float ae2v = __uint_as_float(ae2.y << 16);
  float ae3 = __uint_as_float(ae2.y & 0xffff0000u);
  u32 pk0 = (u32)f2bf(as4.x + ae0);
  u32 pk1 = (u32)f2bf(as4.y + ae1);
  u32 pk2 = (u32)f2bf(as4.z + ae2v);
  u32 pk3 = (u32)f2bf(as4.w + ae3);
  uint4 q;
  q.x = (u32)src;
  q.y = pk0 | (pk1 << 16);
  q.z = pk2 | (pk3 << 16);
  q.w = 0u;
  csr[base + rk] = q;
}

// ---- K4 slow (fallback when ws too small): full MLP (R15 form) ----
__global__ __launch_bounds__(256) void k_edge_s(const float* __restrict__ qraw,
        const float* __restrict__ eattr, const int* __restrict__ eidx,
        const float* __restrict__ Wq1, const float* __restrict__ bq1,
        const float* __restrict__ Wq2, const float* __restrict__ bq2,
        const float* __restrict__ Wt,
        const float* __restrict__ a_src,
        const u32* __restrict__ offs8, const unsigned short* __restrict__ rank,
        uint4* __restrict__ csr){
  __shared__ float sWq1[32], sbq1[8], sWq2[128], sbq2[16], sWt[64];
  int tid = threadIdx.x;
  if (tid < 32) sWq1[tid] = Wq1[tid];
  else if (tid < 40)  sbq1[tid-32]  = bq1[tid-32];
  else if (tid < 168) sWq2[tid-40]  = Wq2[tid-40];
  else if (tid < 184) sbq2[tid-168] = bq2[tid-168];
  else if (tid < 248) sWt[tid-184]  = Wt[tid-184];
  __syncthreads();
  int e = blockIdx.x*256 + tid;
  if (e >= EE) return;
  int shard = (blockIdx.x >> 2) & (NSH-1);

  int src = eidx[e], dst = eidx[EE + e];
  u32 rk = (u32)rank[e];
  float4 qr = *(const float4*)(qraw + (size_t)e*4);
  float4 as4 = *(const float4*)(a_src + (size_t)src*4);
  u32 base = offs8[((size_t)(u32)dst << 3) | shard];

  float t1[8];
  #pragma unroll
  for (int j = 0; j < 8; j++){
    float s = sbq1[j] + qr.x*sWq1[j] + qr.y*sWq1[8+j] + qr.z*sWq1[16+j] + qr.w*sWq1[24+j];
    t1[j] = fmaxf(s, 0.f);
  }
  float ae[4] = {0.f,0.f,0.f,0.f};
  const float* ea = eattr + (size_t)e*16;
  #pragma unroll
  for (int d = 0; d < 16; d++){
    float q = sbq2[d];
    #pragma unroll
    for (int j = 0; j < 8; j++) q += t1[j]*sWq2[j*16 + d];
    float v = ea[d] + q;
    #pragma unroll
    for (int h = 0; h < 4; h++) ae[h] += v * sWt[d*4 + h];
  }
  u32 pk0 = (u32)f2bf(as4.x + ae[0]);
  u32 pk1 = (u32)f2bf(as4.y + ae[1]);
  u32 pk2 = (u32)f2bf(as4.z + ae[2]);
  u32 pk3 = (u32)f2bf(as4.w + ae[3]);
  uint4 q;
  q.x = (u32)src;
  q.y = pk0 | (pk1 << 16);
  q.z = pk2 | (pk3 << 16);
  q.w = 0u;
  csr[base + rk] = q;
}

// ---- K5: aggregation (exact R15 form: 2 nodes/wave, 16B/lane, 4x unroll) ----
__global__ __launch_bounds__(256) void k_agg(const __hip_bfloat16* __restrict__ zs,
        const uint4* __restrict__ csr, const u32* __restrict__ offs8,
        const float* __restrict__ a_dst,
        const float* __restrict__ cvec, float* __restrict__ out){
  int tid = threadIdx.x;
  int w = tid >> 6, lane = tid & 63;
  int half = lane >> 5, sl = lane & 31;
  int n = blockIdx.x*8 + w*2 + half;    // grid = NN/8 exactly
  int h = sl >> 3, c8 = sl & 7;
  u32 p0 = offs8[(size_t)n << 3], p1 = offs8[((size_t)n << 3) + 8];
  float adv = a_dst[((size_t)n << 2) + h];
  int sh = (h & 1) ? 0 : 16;
  u32 lb = (u32)(h*128 + c8*16);
  const char* zb = (const char*)zs;
  float d = 0.f;
  float a0=0.f,a1=0.f,a2=0.f,a3=0.f,a4=0.f,a5=0.f,a6=0.f,a7=0.f;
  u32 p = p0;
  for (; p + 4 <= p1; p += 4){
    uint4 q0 = csr[p+0], q1 = csr[p+1], q2 = csr[p+2], q3 = csr[p+3];
    u32 s0 = q0.x, s1 = q1.x, s2 = q2.x, s3 = q3.x;
    u32 w0p = (h < 2) ? q0.y : q0.z,  w1p = (h < 2) ? q1.y : q1.z;
    u32 w2p = (h < 2) ? q2.y : q2.z,  w3p = (h < 2) ? q3.y : q3.z;
    uint4 v0 = *(const uint4*)(zb + ((s0 << 9) + lb));
    uint4 v1 = *(const uint4*)(zb + ((s1 << 9) + lb));
    uint4 v2 = *(const uint4*)(zb + ((s2 << 9) + lb));
    uint4 v3 = *(const uint4*)(zb + ((s3 << 9) + lb));
    float al0 = __uint_as_float((w0p << sh) & 0xffff0000u) + adv;
    float al1 = __uint_as_float((w1p << sh) & 0xffff0000u) + adv;
    float al2 = __uint_as_float((w2p << sh) & 0xffff0000u) + adv;
    float al3 = __uint_as_float((w3p << sh) & 0xffff0000u) + adv;
    al0 = fmaxf(al0, 0.f) + NEG*fminf(al0, 0.f);
    al1 = fmaxf(al1, 0.f) + NEG*fminf(al1, 0.f);
    al2 = fmaxf(al2, 0.f) + NEG*fminf(al2, 0.f);
    al3 = fmaxf(al3, 0.f) + NEG*fminf(al3, 0.f);
    float w0 = __expf(al0), w1 = __expf(al1), w2 = __expf(al2), w3 = __expf(al3);
    a0 += w0*__uint_as_float(v0.x << 16)         + w1*__uint_as_float(v1.x << 16)
        + w2*__uint_as_float(v2.x << 16)         + w3*__uint_as_float(v3.x << 16);
    a1 += w0*__uint_as_float(v0.x & 0xffff0000u) + w1*__uint_as_float(v1.x & 0xffff0000u)
        + w2*__uint_as_float(v2.x & 0xffff0000u) + w3*__uint_as_float(v3.x & 0xffff0000u);
    a2 += w0*__uint_as_float(v0.y << 16)         + w1*__uint_as_float(v1.y << 16)
        + w2*__uint_as_float(v2.y << 16)         + w3*__uint_as_float(v3.y << 16);
    a3 += w0*__uint_as_float(v0.y & 0xffff0000u) + w1*__uint_as_float(v1.y & 0xffff0000u)
        + w2*__uint_as_float(v2.y & 0xffff0000u) + w3*__uint_as_float(v3.y & 0xffff0000u);
    a4 += w0*__uint_as_float(v0.z << 16)         + w1*__uint_as_float(v1.z << 16)
        + w2*__uint_as_float(v2.z << 16)         + w3*__uint_as_float(v3.z << 16);
    a5 += w0*__uint_as_float(v0.z & 0xffff0000u) + w1*__uint_as_float(v1.z & 0xffff0000u)
        + w2*__uint_as_float(v2.z & 0xffff0000u) + w3*__uint_as_float(v3.z & 0xffff0000u);
    a6 += w0*__uint_as_float(v0.w << 16)         + w1*__uint_as_float(v1.w << 16)
        + w2*__uint_as_float(v2.w << 16)         + w3*__uint_as_float(v3.w << 16);
    a7 += w0*__uint_as_float(v0.w & 0xffff0000u) + w1*__uint_as_float(v1.w & 0xffff0000u)
        + w2*__uint_as_float(v2.w & 0xffff0000u) + w3*__uint_as_float(v3.w & 0xffff0000u);
    d  += (w0 + w1) + (w2 + w3);
  }
  for (; p < p1; p++){
    uint4 q0 = csr[p];
    u32 wp = (h < 2) ? q0.y : q0.z;
    float al = __uint_as_float((wp << sh) & 0xffff0000u) + adv;
    al = fmaxf(al, 0.f) + NEG*fminf(al, 0.f);
    float w0 = __expf(al);
    uint4 v0 = *(const uint4*)(zb + ((q0.x << 9) + lb));
    a0 += w0*__uint_as_float(v0.x << 16);
    a1 += w0*__uint_as_float(v0.x & 0xffff0000u);
    a2 += w0*__uint_as_float(v0.y << 16);
    a3 += w0*__uint_as_float(v0.y & 0xffff0000u);
    a4 += w0*__uint_as_float(v0.z << 16);
    a5 += w0*__uint_as_float(v0.z & 0xffff0000u);
    a6 += w0*__uint_as_float(v0.w << 16);
    a7 += w0*__uint_as_float(v0.w & 0xffff0000u);
    d  += w0;
  }
  float inv = (d > 0.f) ? 0.25f / d : 0.f;
  a0 *= inv; a1 *= inv; a2 *= inv; a3 *= inv;
  a4 *= inv; a5 *= inv; a6 *= inv; a7 *= inv;
  a0 += __shfl_xor(a0, 8);  a1 += __shfl_xor(a1, 8);
  a2 += __shfl_xor(a2, 8);  a3 += __shfl_xor(a3, 8);
  a4 += __shfl_xor(a4, 8);  a5 += __shfl_xor(a5, 8);
  a6 += __shfl_xor(a6, 8);  a7 += __shfl_xor(a7, 8);
  a0 += __shfl_xor(a0, 16); a1 += __shfl_xor(a1, 16);
  a2 += __shfl_xor(a2, 16); a3 += __shfl_xor(a3, 16);
  a4 += __shfl_xor(a4, 16); a5 += __shfl_xor(a5, 16);
  a6 += __shfl_xor(a6, 16); a7 += __shfl_xor(a7, 16);
  if (h == 0){
    const float* cv = cvec + c8*8;
    float4 o0, o1v;
    o0.x  = fmaxf(a0 + cv[0], 0.f);
    o0.y  = fmaxf(a1 + cv[1], 0.f);
    o0.z  = fmaxf(a2 + cv[2], 0.f);
    o0.w  = fmaxf(a3 + cv[3], 0.f);
    o1v.x = fmaxf(a4 + cv[4], 0.f);
    o1v.y = fmaxf(a5 + cv[5], 0.f);
    o1v.z = fmaxf(a6 + cv[6], 0.f);
    o1v.w = fmaxf(a7 + cv[7], 0.f);
    float* op = out + (size_t)n*64 + c8*8;
    *(float4*)op = o0;
    *(float4*)(op + 4) = o1v;
  }
}

extern "C" void kernel_launch(void* const* d_in, const int* in_sizes, int n_in,
                              void* d_out, int out_size, void* d_ws, size_t ws_size,
                              hipStream_t stream){
  const float* x       = (const float*)d_in[0];
  const int*   eidx    = (const int*)d_in[1];
  const float* eattr   = (const float*)d_in[2];
  const float* qraw    = (const float*)d_in[3];
  const float* ns      = (const float*)d_in[4];
  const float* Wg      = (const float*)d_in[5];
  const float* att_src = (const float*)d_in[6];
  const float* att_dst = (const float*)d_in[7];
  const float* W_edge  = (const float*)d_in[8];
  const float* att_edge= (const float*)d_in[9];
  const float* b_gat   = (const float*)d_in[10];
  const float* Wq1     = (const float*)d_in[11];
  const float* bq1     = (const float*)d_in[12];
  const float* Wq2     = (const float*)d_in[13];
  const float* bq2     = (const float*)d_in[14];
  const float* W_c     = (const float*)d_in[15];
  const float* b_c     = (const float*)d_in[16];
  float* out = (float*)d_out;

  char* ws = (char*)d_ws;
  __hip_bfloat16* zs = (__hip_bfloat16*)ws;              // 0          (25,600,000)
  uint4* csr      = (uint4*)(ws + 25600000);             // 25.6M..38.4M (12.8MB)
  u32* deg8       = (u32*)(ws + 25600000);               // ALIAS: dead before csr written
  u32* offs8      = (u32*)(ws + 38400000);               // 1,600,064
  float* a_src    = (float*)(ws + 41600064);             //   800,000
  float* a_dst    = (float*)(ws + 42400064);             //   800,000
  unsigned short* rank = (unsigned short*)(ws + 43200064); // 1,600,000
  u32* bsum       = (u32*)(ws + 44800064);               //     4,096
  unsigned short* WzB = (unsigned short*)(ws + 44804160); //    65,536
  uint2* avp      = (uint2*)(ws + 44869696);             //     4,096
  float* Wt       = (float*)(ws + 44873792);             //       256
  float* cvec     = (float*)(ws + 44874048);             //       256
  uint2* aeb      = (uint2*)(ws + 44874304);             // 6,400,000 (if ws allows)
  int big = (ws_size >= (size_t)44874304 + 6400000) ? 1 : 0;

  k_pre_all<<<130+NZB,  256, 0, stream>>>(Wg, W_c, W_edge, att_edge, b_c, ns, b_gat,
                                          att_src, att_dst, WzB, Wt, cvec, avp, deg8);
  k_main   <<<NMB,      256, 0, stream>>>(x, WzB, avp, eidx + EE, qraw, eattr,
                                          Wq1, bq1, Wq2, bq2, Wt,
                                          zs, a_src, a_dst, deg8, rank, aeb, big);
  k_scan1  <<<NSB2,    1024, 0, stream>>>(deg8, offs8, bsum);
  k_scan2  <<<NSB2,    1024, 0, stream>>>(offs8, bsum);
  if (big){
    k_edge_f<<<3125,    256, 0, stream>>>(eidx, rank, aeb, a_src, offs8, csr);
  } else {
    k_edge_s<<<3125,    256, 0, stream>>>(qraw, eattr, eidx, Wq1, bq1, Wq2, bq2, Wt,
                                          a_src, offs8, rank, csr);
  }
  k_agg    <<<6250,     256, 0, stream>>>(zs, csr, offs8, a_dst, cvec, out);
}